// Round 6
// baseline (747.582 us; speedup 1.0000x reference)
//
#include <hip/hip_runtime.h>

#define B_SIZE 1024
#define T_LEN  256
#define D_IN   64
#define HC     32

typedef int   v2i_t __attribute__((ext_vector_type(2)));
typedef float v2f   __attribute__((ext_vector_type(2)));

__device__ __forceinline__ float frcp(float x){ return __builtin_amdgcn_rcpf(x); }
__device__ __forceinline__ float rfl(float x){
    return __uint_as_float(__builtin_amdgcn_readfirstlane(__float_as_uint(x)));
}
__device__ __forceinline__ float rdlane(float x, int l){
    return __int_as_float(__builtin_amdgcn_readlane(__float_as_int(x), l));
}
__device__ __forceinline__ float ftanh(float x){
    return 1.f - 2.f*frcp(__expf(2.f*x) + 1.f);
}
__device__ __forceinline__ float fsigmoid(float x){
    return frcp(1.f + __expf(-x));
}

template<int CTRL>
__device__ __forceinline__ int dppmov(int x){
    return __builtin_amdgcn_update_dpp(x, x, CTRL, 0xF, 0xF, false);
}

// xor within 16-lane rows, masks 1..15, pure DPP (1-2 ops)
template<int M>
__device__ __forceinline__ int dpp_xor(int x){
    static_assert(M >= 1 && M <= 15, "dpp_xor mask");
    constexpr int hi = M & 12;
    constexpr int q  = (hi == 4 || hi == 12) ? ((M & 3) ^ 3) : (M & 3);
    if constexpr (q == 1) x = dppmov<0xB1>(x);
    else if constexpr (q == 2) x = dppmov<0x4E>(x);
    else if constexpr (q == 3) x = dppmov<0x1B>(x);
    if constexpr (hi == 4)       x = dppmov<0x141>(x);   // ^7 -> with ^3 pre = ^4
    else if constexpr (hi == 8)  x = dppmov<0x128>(x);   // row_ror:8 = ^8
    else if constexpr (hi == 12) x = dppmov<0x140>(x);   // row_mirror = ^15
    return x;
}

#if defined(__has_builtin)
#  if __has_builtin(__builtin_amdgcn_permlane16_swap)
#    define HAVE_PL16 1
#  endif
#endif

// value of lane (lane ^ M) — fully VALU (R5 HW-verified xor-trick for swaps):
//  bits 0-3 -> DPP mirrors; bit4 -> permlane16_swap; bit5 -> permlane32_swap
template<int M>
__device__ __forceinline__ float xshuf(float xf){
    if constexpr (M == 0) return xf;
    int x = __float_as_int(xf);
    if constexpr (M & 15) x = dpp_xor<M & 15>(x);
    if constexpr (M & 16){
#ifdef HAVE_PL16
        v2i_t r = __builtin_amdgcn_permlane16_swap(x, x, false, false);
        x = r.x ^ r.y ^ x;   // {r.x,r.y} jointly hold {own,partner} -> partner
#else
        x = __builtin_amdgcn_ds_swizzle(x, (16 << 10) | 0x1F);
#endif
    }
    if constexpr (M & 32){
        v2i_t r = __builtin_amdgcn_permlane32_swap(x, x, false, false);
        x = r.x ^ r.y ^ x;
    }
    return __int_as_float(x);
}

// ---- compile-time GF(2) tracking of the CNOT-ring basis relabeling (R3-verified) ----
struct QMasks { int M[3][6]; int S[3][6]; int R[6]; };
constexpr QMasks qmasks(){
    QMasks qm{};
    unsigned m[6], n[6];
    for (int i = 0; i < 6; i++){ m[i] = 1u << i; n[i] = 1u << i; }
    for (int l = 0; l < 3; l++){
        for (int q = 0; q < 6; q++){
            unsigned u = m[q], r = 0;
            for (int i = 0; i < 6; i++) if ((u >> i) & 1u) r |= (32u >> i);
            qm.S[l][q] = (int)r;
            unsigned u2 = 0;
            for (int i = 0; i < 6; i++) u2 |= ((n[i] >> q) & 1u) << i;
            unsigned r2 = 0;
            for (int i = 0; i < 6; i++) if ((u2 >> i) & 1u) r2 |= (32u >> i);
            qm.M[l][q] = (int)r2;
        }
        for (int q = 0; q < 6; q++) m[(q + 1) % 6] ^= m[q];
        n[0] ^= n[5];
        for (int q = 4; q >= 0; q--) n[q + 1] ^= n[q];
    }
    for (int i = 0; i < 6; i++){
        unsigned u = m[i], r = 0;
        for (int j = 0; j < 6; j++) if ((u >> j) & 1u) r |= (32u >> j);
        qm.R[i] = (int)r;
    }
    return qm;
}
constexpr QMasks QM = qmasks();

// ---------------- conv0 (R1-proven): x (B,T,64) -> t0 (B,32,T) ----------------
__global__ __launch_bounds__(256) void conv0_kernel(const float* __restrict__ x,
    const float* __restrict__ w0, const float* __restrict__ b0, float* __restrict__ out)
{
    __shared__ float xs[130*65];
    __shared__ float wl[192*32];
    const int tid = threadIdx.x;
    const int b  = blockIdx.x >> 1;
    const int s0 = (blockIdx.x & 1) * 128;

    for (int idx = tid; idx < 130*64; idx += 256){
        int r = idx >> 6, d = idx & 63;
        int s = s0 - 1 + r;
        float v = 0.f;
        if (s >= 0 && s < T_LEN) v = x[(size_t)b*(T_LEN*D_IN) + (size_t)s*D_IN + d];
        xs[r*65 + d] = v;
    }
    for (int idx = tid; idx < 192*32; idx += 256){
        int r = idx >> 5, c = idx & 31;
        wl[idx] = w0[c*192 + r];
    }
    __syncthreads();

    const int c0 = (tid & 7) * 4;
    const int sl = (tid >> 3) * 4;
    float acc[4][4];
    #pragma unroll
    for (int ci = 0; ci < 4; ci++){
        float bb = b0[c0+ci];
        #pragma unroll
        for (int m = 0; m < 4; m++) acc[ci][m] = bb;
    }
    for (int d = 0; d < 64; d++){
        float xv[6];
        #pragma unroll
        for (int o = 0; o < 6; o++) xv[o] = xs[(sl+o)*65 + d];
        #pragma unroll
        for (int kk = 0; kk < 3; kk++){
            const float4 wv = *(const float4*)&wl[(d*3+kk)*32 + c0];
            float w4[4] = {wv.x, wv.y, wv.z, wv.w};
            #pragma unroll
            for (int ci = 0; ci < 4; ci++)
                #pragma unroll
                for (int m = 0; m < 4; m++)
                    acc[ci][m] += xv[m+kk]*w4[ci];
        }
    }
    #pragma unroll
    for (int ci = 0; ci < 4; ci++){
        float4 v;
        v.x = fmaxf(acc[ci][0], 0.f); v.y = fmaxf(acc[ci][1], 0.f);
        v.z = fmaxf(acc[ci][2], 0.f); v.w = fmaxf(acc[ci][3], 0.f);
        *(float4*)&out[(size_t)b*(HC*T_LEN) + (size_t)(c0+ci)*T_LEN + (s0+sl)] = v;
    }
}

// ------------- mid conv (R1-proven): (B,32,T) -> (B,32,T) or (T,B,32) -------------
template<bool TOUT>
__global__ __launch_bounds__(256) void convm_kernel(const float* __restrict__ in,
    const float* __restrict__ w, const float* __restrict__ bias, float* __restrict__ out)
{
    __shared__ float xs[130*33];
    __shared__ float wl[96*32];
    const int tid = threadIdx.x;
    const int b  = blockIdx.x >> 1;
    const int s0 = (blockIdx.x & 1) * 128;

    for (int idx = tid; idx < 32*130; idx += 256){
        int ci = idx / 130; int r = idx - ci*130;
        int s = s0 - 1 + r;
        float v = 0.f;
        if (s >= 0 && s < T_LEN) v = in[(size_t)b*(HC*T_LEN) + (size_t)ci*T_LEN + s];
        xs[r*33 + ci] = v;
    }
    for (int idx = tid; idx < 96*32; idx += 256){
        int r = idx >> 5, c = idx & 31;
        wl[idx] = w[c*96 + r];
    }
    __syncthreads();

    const int c0 = (tid & 7) * 4;
    const int sl = (tid >> 3) * 4;
    float acc[4][4];
    #pragma unroll
    for (int ci = 0; ci < 4; ci++){
        float bb = bias[c0+ci];
        #pragma unroll
        for (int m = 0; m < 4; m++) acc[ci][m] = bb;
    }
    for (int ci2 = 0; ci2 < 32; ci2++){
        float xv[6];
        #pragma unroll
        for (int o = 0; o < 6; o++) xv[o] = xs[(sl+o)*33 + ci2];
        #pragma unroll
        for (int kk = 0; kk < 3; kk++){
            const float4 wv = *(const float4*)&wl[(ci2*3+kk)*32 + c0];
            float w4[4] = {wv.x, wv.y, wv.z, wv.w};
            #pragma unroll
            for (int ci = 0; ci < 4; ci++)
                #pragma unroll
                for (int m = 0; m < 4; m++)
                    acc[ci][m] += xv[m+kk]*w4[ci];
        }
    }
    if (!TOUT){
        #pragma unroll
        for (int ci = 0; ci < 4; ci++){
            float4 v;
            v.x = fmaxf(acc[ci][0], 0.f); v.y = fmaxf(acc[ci][1], 0.f);
            v.z = fmaxf(acc[ci][2], 0.f); v.w = fmaxf(acc[ci][3], 0.f);
            *(float4*)&out[(size_t)b*(HC*T_LEN) + (size_t)(c0+ci)*T_LEN + (s0+sl)] = v;
        }
    } else {
        #pragma unroll
        for (int m = 0; m < 4; m++){
            int s = s0 + sl + m;
            float4 v;
            v.x = fmaxf(acc[0][m], 0.f); v.y = fmaxf(acc[1][m], 0.f);
            v.z = fmaxf(acc[2][m], 0.f); v.w = fmaxf(acc[3][m], 0.f);
            *(float4*)&out[(size_t)s*(B_SIZE*HC) + (size_t)b*HC + c0] = v;
        }
    }
}

// ------- gates precompute: G[pair][r] = bih[r]+bhh[r] + Wih[r,:] . tS[pair,:] -------
// pair = s*B + b (tS is (T,B,32) contiguous). 8 pairs/block, 256 threads.
__global__ __launch_bounds__(256) void gates_kernel(const float* __restrict__ tS,
    const float* __restrict__ Wih, const float* __restrict__ bih,
    const float* __restrict__ bhh, float* __restrict__ G)
{
    __shared__ float xs[8][32];
    const int tid = threadIdx.x;
    const size_t pair0 = (size_t)blockIdx.x * 8;

    { int p = tid >> 5, j = tid & 31;
      xs[p][j] = tS[pair0*32 + (size_t)p*32 + j]; }
    __syncthreads();

    const int r = tid & 127;
    const int half = tid >> 7;
    float4 wr[8];
    #pragma unroll
    for (int j4 = 0; j4 < 8; j4++) wr[j4] = ((const float4*)Wih)[r*8 + j4];
    const float br = bih[r] + bhh[r];

    #pragma unroll
    for (int pp = 0; pp < 4; pp++){
        const int p = half + pp*2;
        float a0 = br, a1 = 0.f, a2 = 0.f, a3 = 0.f;
        #pragma unroll
        for (int j4 = 0; j4 < 8; j4++){
            const float4 xv = *(const float4*)&xs[p][j4*4];
            a0 += wr[j4].x*xv.x; a1 += wr[j4].y*xv.y;
            a2 += wr[j4].z*xv.z; a3 += wr[j4].w*xv.w;
        }
        G[(pair0 + p)*128 + r] = (a0+a1)+(a2+a3);
    }
}

// ------------- scan v3: G-fed, DS-free inner loop, packed fp32 math -------------
__global__ __launch_bounds__(256, 1) void scan_kernel(
    const float* __restrict__ G,   const float* __restrict__ Whh,
    const float* __restrict__ qw,  const float* __restrict__ Wfc,
    const float* __restrict__ bfc, const float* __restrict__ Wout,
    const float* __restrict__ bout, float* __restrict__ out)
{
    const unsigned lane = threadIdx.x & 63u;
    const int wv   = threadIdx.x >> 6;
    const int b    = __builtin_amdgcn_readfirstlane(blockIdx.x * 4 + wv);
    const int r1 = lane, r2 = lane + 64;       // gate rows: [i f | g o]
    const int k  = lane & 31;

    // packed recurrent weight rows {Whh[r1][j], Whh[r2][j]} (64 VGPRs)
    v2f uAB[32];
    #pragma unroll
    for (int j4 = 0; j4 < 8; j4++){
        float4 d_ = ((const float4*)Whh)[r1*8 + j4];
        float4 e  = ((const float4*)Whh)[r2*8 + j4];
        uAB[j4*4+0] = v2f{d_.x, e.x}; uAB[j4*4+1] = v2f{d_.y, e.y};
        uAB[j4*4+2] = v2f{d_.z, e.z}; uAB[j4*4+3] = v2f{d_.w, e.w};
    }

    float wfcr[6];
    #pragma unroll
    for (int j = 0; j < 6; j++) wfcr[j] = Wfc[k*6 + j];
    const float bfcl  = bfc[k];
    const float woutl = (lane < 32) ? Wout[k] : 0.f;
    const float boutv = bout[0];

    float cgv[18], ssin[18];
    #pragma unroll
    for (int g = 0; g < 18; g++){
        int l = g / 6, q = g % 6;
        float a = 0.5f * qw[g];
        float cv = __cosf(a), sv = __sinf(a);
        cgv[g] = rfl(cv);
        unsigned sm = (unsigned)QM.S[l][q];
        ssin[g] = (__builtin_popcount(sm & lane) & 1) ? sv : -sv;
    }
    float wsgn[6];
    #pragma unroll
    for (int j = 0; j < 6; j++) wsgn[j] = (lane & (1u << j)) ? -1.f : 1.f;
    const bool qs[6] = { (lane & 32u) != 0, (lane & 16u) != 0, (lane & 8u) != 0,
                         (lane & 4u) != 0,  (lane & 2u) != 0,  (lane & 1u) != 0 };

    float h = 0.f, c = 0.f;
    const float* gbase = G + (size_t)b*128;
    float g1 = gbase[r1], g2 = gbase[r2];

    #pragma clang loop unroll(disable)
    for (int s = 0; s < T_LEN; s++){
        const float cg1 = g1, cg2 = g2;
        { // prefetch next step's two gate inputs
            int s2 = (s + 1 < T_LEN) ? s + 1 : s;
            const float* gn = gbase + (size_t)s2*(B_SIZE*128);
            g1 = gn[r1]; g2 = gn[r2];
        }

        // ---- recurrent dot: 32 packed FMAs over 4 chains ----
        v2f a0 = v2f{cg1, cg2}, a1 = v2f{0.f,0.f}, a2 = v2f{0.f,0.f}, a3 = v2f{0.f,0.f};
        #pragma unroll
        for (int j = 0; j < 32; j += 4){
            float h0 = rdlane(h, j),   h1 = rdlane(h, j+1);
            float h2 = rdlane(h, j+2), h3 = rdlane(h, j+3);
            a0 += h0*uAB[j]; a1 += h1*uAB[j+1]; a2 += h2*uAB[j+2]; a3 += h3*uAB[j+3];
        }
        v2f accv = (a0+a1)+(a2+a3);
        float acc1 = accv.x, acc2 = accv.y;

        float sigA = fsigmoid(acc1);                 // low: sig(i), high: sig(f)
        float argB = (lane < 32) ? acc2 : 0.5f*acc2; // low: tanh(g), high: sig(o)
        float tt   = ftanh(argB);
        float actB = (lane < 32) ? tt : (0.5f + 0.5f*tt);
        float fsig = xshuf<32>(sigA);
        float osig = xshuf<32>(actB);
        c = fsig*c + sigA*actB;
        float hn = osig * ftanh(c);

        // ---- logistic + henon ----
        hn = 3.99f * hn * (1.f - hn);
        float x0 = rdlane(hn, 0), y0 = rdlane(hn, 1);
        float xnv = 1.f - 1.4f*x0*x0 + y0;
        float ynv = 0.3f * x0;

        // ---- product-state init ----
        float ang[6];
        ang[0] = 0.5f*xnv; ang[1] = 0.5f*ynv;
        ang[2] = 0.5f*rdlane(hn, 2); ang[3] = 0.5f*rdlane(hn, 3);
        ang[4] = 0.5f*rdlane(hn, 4); ang[5] = 0.5f*rdlane(hn, 5);
        float ca[6], sa[6];
        #pragma unroll
        for (int j = 0; j < 6; j++){ ca[j] = __cosf(ang[j]); sa[j] = __sinf(ang[j]); }

        float fr[6], fi[6];
        #pragma unroll
        for (int i = 0; i < 6; i++){
            const int i1 = (i+1)%6, i2 = (i+2)%6;
            float cx=ca[i], sx=sa[i], cy=ca[i1], sy=sa[i1], cz=ca[i2], sz=sa[i2];
            float w0r = cy*cx, w0i = sy*sx;
            float w1r = sy*cx, w1i = -cy*sx;
            float q0r = cz*w0r + sz*w0i, q0i = cz*w0i - sz*w0r;
            float q1r = cz*w1r - sz*w1i, q1i = cz*w1i + sz*w1r;
            fr[i] = qs[i] ? q1r : q0r;
            fi[i] = qs[i] ? q1i : q0i;
        }
        v2f t01 = v2f{fr[0]*fr[1] - fi[0]*fi[1], fr[0]*fi[1] + fi[0]*fr[1]};
        v2f t23 = v2f{fr[2]*fr[3] - fi[2]*fi[3], fr[2]*fi[3] + fi[2]*fr[3]};
        v2f t45 = v2f{fr[4]*fr[5] - fi[4]*fi[5], fr[4]*fi[5] + fi[4]*fr[5]};
        v2f t03 = v2f{t01.x*t23.x - t01.y*t23.y, t01.x*t23.y + t01.y*t23.x};
        v2f av  = v2f{t03.x*t45.x - t03.y*t45.y, t03.x*t45.y + t03.y*t45.x};

        // ---- entangling layers: packed {re,im} update, all-VALU exchanges ----
        #define GATE(L,Q) { \
            constexpr int MM = QM.M[L][Q]; \
            v2f bv; bv.x = xshuf<MM>(av.x); bv.y = xshuf<MM>(av.y); \
            av = cgv[(L)*6+(Q)]*av + ssin[(L)*6+(Q)]*bv; }
        GATE(0,0) GATE(0,1) GATE(0,2) GATE(0,3) GATE(0,4) GATE(0,5)
        GATE(1,0) GATE(1,1) GATE(1,2) GATE(1,3) GATE(1,4) GATE(1,5)
        GATE(2,0) GATE(2,1) GATE(2,2) GATE(2,3) GATE(2,4) GATE(2,5)
        #undef GATE

        // ---- expvals: Walsh-Hadamard butterfly, pick rows of Pi^-3 ----
        float wp = av.x*av.x + av.y*av.y;
        wp = wsgn[0]*wp + xshuf< 1>(wp);
        wp = wsgn[1]*wp + xshuf< 2>(wp);
        wp = wsgn[2]*wp + xshuf< 4>(wp);
        wp = wsgn[3]*wp + xshuf< 8>(wp);
        wp = wsgn[4]*wp + xshuf<16>(wp);
        wp = wsgn[5]*wp + xshuf<32>(wp);
        float ev0 = rdlane(wp, QM.R[0]), ev1 = rdlane(wp, QM.R[1]);
        float ev2 = rdlane(wp, QM.R[2]), ev3 = rdlane(wp, QM.R[3]);
        float ev4 = rdlane(wp, QM.R[4]), ev5 = rdlane(wp, QM.R[5]);

        float upd = bfcl + (wfcr[0]*ev0 + wfcr[1]*ev1)
                         + (wfcr[2]*ev2 + wfcr[3]*ev3)
                         + (wfcr[4]*ev4 + wfcr[5]*ev5);

        float hsel = hn;
        hsel = (lane == 0u) ? xnv : hsel;
        hsel = (lane == 1u) ? ynv : hsel;
        h = hsel + upd;
    }

    float pv = (lane < 32) ? h*woutl : 0.f;
    #pragma unroll
    for (int off = 32; off; off >>= 1) pv += __shfl_xor(pv, off, 64);
    if (lane == 0) out[b] = fsigmoid(pv + boutv);
}

// ---------------- legacy scan (R5-proven) — fallback if ws too small ----------------
__global__ __launch_bounds__(256, 1) void scan_legacy(
    const float* __restrict__ tS,
    const float* __restrict__ Wih, const float* __restrict__ Whh,
    const float* __restrict__ bih, const float* __restrict__ bhh,
    const float* __restrict__ qw,  const float* __restrict__ Wfc,
    const float* __restrict__ bfc, const float* __restrict__ Wout,
    const float* __restrict__ bout, float* __restrict__ out)
{
    const unsigned lane = threadIdx.x & 63u;
    const int wv   = threadIdx.x >> 6;
    const int b    = __builtin_amdgcn_readfirstlane(blockIdx.x * 4 + wv);
    const int r1 = lane, r2 = lane + 64;
    const int k  = lane & 31;

    float wA[32], wB[32], uA[32], uB[32];
    #pragma unroll
    for (int j4 = 0; j4 < 8; j4++){
        float4 a  = ((const float4*)Wih)[r1*8 + j4];
        float4 c_ = ((const float4*)Wih)[r2*8 + j4];
        float4 d_ = ((const float4*)Whh)[r1*8 + j4];
        float4 e  = ((const float4*)Whh)[r2*8 + j4];
        wA[j4*4+0]=a.x;  wA[j4*4+1]=a.y;  wA[j4*4+2]=a.z;  wA[j4*4+3]=a.w;
        wB[j4*4+0]=c_.x; wB[j4*4+1]=c_.y; wB[j4*4+2]=c_.z; wB[j4*4+3]=c_.w;
        uA[j4*4+0]=d_.x; uA[j4*4+1]=d_.y; uA[j4*4+2]=d_.z; uA[j4*4+3]=d_.w;
        uB[j4*4+0]=e.x;  uB[j4*4+1]=e.y;  uB[j4*4+2]=e.z;  uB[j4*4+3]=e.w;
    }
    const float bias1 = bih[r1] + bhh[r1];
    const float bias2 = bih[r2] + bhh[r2];

    float wfcr[6];
    #pragma unroll
    for (int j = 0; j < 6; j++) wfcr[j] = Wfc[k*6 + j];
    const float bfcl  = bfc[k];
    const float woutl = (lane < 32) ? Wout[k] : 0.f;
    const float boutv = bout[0];

    float cgv[18], ssin[18];
    #pragma unroll
    for (int g = 0; g < 18; g++){
        int l = g / 6, q = g % 6;
        float a = 0.5f * qw[g];
        float cv = __cosf(a), sv = __sinf(a);
        cgv[g] = rfl(cv);
        unsigned sm = (unsigned)QM.S[l][q];
        ssin[g] = (__builtin_popcount(sm & lane) & 1) ? sv : -sv;
    }
    float wsgn[6];
    #pragma unroll
    for (int j = 0; j < 6; j++) wsgn[j] = (lane & (1u << j)) ? -1.f : 1.f;
    const bool qs[6] = { (lane & 32u) != 0, (lane & 16u) != 0, (lane & 8u) != 0,
                         (lane & 4u) != 0,  (lane & 2u) != 0,  (lane & 1u) != 0 };

    float h = 0.f, c = 0.f;
    const float* xbase = tS + (size_t)b * HC;

    float4 xf[8];
    #pragma unroll
    for (int j4 = 0; j4 < 8; j4++) xf[j4] = ((const float4*)xbase)[j4];

    #pragma clang loop unroll(disable)
    for (int s = 0; s < T_LEN; s++){
        float xt[32];
        #pragma unroll
        for (int j4 = 0; j4 < 8; j4++){
            xt[j4*4+0]=xf[j4].x; xt[j4*4+1]=xf[j4].y; xt[j4*4+2]=xf[j4].z; xt[j4*4+3]=xf[j4].w;
        }
        {
            int s2 = (s + 1 < T_LEN) ? s + 1 : s;
            const float4* np_ = (const float4*)(xbase + (size_t)s2*(B_SIZE*HC));
            #pragma unroll
            for (int j4 = 0; j4 < 8; j4++) xf[j4] = np_[j4];
        }

        float a1a = bias1, a1b = 0.f, a2a = bias2, a2b = 0.f;
        #pragma unroll
        for (int j = 0; j < 32; j += 2){
            a1a += xt[j]*wA[j];     a1b += xt[j+1]*wA[j+1];
            a2a += xt[j]*wB[j];     a2b += xt[j+1]*wB[j+1];
        }
        #pragma unroll
        for (int j = 0; j < 32; j += 2){
            float h0 = rdlane(h, j), h1 = rdlane(h, j+1);
            a1a += h0*uA[j];   a1b += h1*uA[j+1];
            a2a += h0*uB[j];   a2b += h1*uB[j+1];
        }
        float acc1 = a1a + a1b, acc2 = a2a + a2b;

        float sigA = fsigmoid(acc1);
        float argB = (lane < 32) ? acc2 : 0.5f*acc2;
        float tt   = ftanh(argB);
        float actB = (lane < 32) ? tt : (0.5f + 0.5f*tt);
        float fsig = xshuf<32>(sigA);
        float osig = xshuf<32>(actB);
        c = fsig*c + sigA*actB;
        float hn = osig * ftanh(c);

        hn = 3.99f * hn * (1.f - hn);
        float x0 = rdlane(hn, 0), y0 = rdlane(hn, 1);
        float xnv = 1.f - 1.4f*x0*x0 + y0;
        float ynv = 0.3f * x0;

        float ang[6];
        ang[0] = 0.5f*xnv; ang[1] = 0.5f*ynv;
        ang[2] = 0.5f*rdlane(hn, 2); ang[3] = 0.5f*rdlane(hn, 3);
        ang[4] = 0.5f*rdlane(hn, 4); ang[5] = 0.5f*rdlane(hn, 5);
        float ca[6], sa[6];
        #pragma unroll
        for (int j = 0; j < 6; j++){ ca[j] = __cosf(ang[j]); sa[j] = __sinf(ang[j]); }

        float fr[6], fi[6];
        #pragma unroll
        for (int i = 0; i < 6; i++){
            const int i1 = (i+1)%6, i2 = (i+2)%6;
            float cx=ca[i], sx=sa[i], cy=ca[i1], sy=sa[i1], cz=ca[i2], sz=sa[i2];
            float w0r = cy*cx, w0i = sy*sx;
            float w1r = sy*cx, w1i = -cy*sx;
            float q0r = cz*w0r + sz*w0i, q0i = cz*w0i - sz*w0r;
            float q1r = cz*w1r - sz*w1i, q1i = cz*w1i + sz*w1r;
            fr[i] = qs[i] ? q1r : q0r;
            fi[i] = qs[i] ? q1i : q0i;
        }
        float t01r = fr[0]*fr[1] - fi[0]*fi[1], t01i = fr[0]*fi[1] + fi[0]*fr[1];
        float t23r = fr[2]*fr[3] - fi[2]*fi[3], t23i = fr[2]*fi[3] + fi[2]*fr[3];
        float t45r = fr[4]*fr[5] - fi[4]*fi[5], t45i = fr[4]*fi[5] + fi[4]*fr[5];
        float t03r = t01r*t23r - t01i*t23i,     t03i = t01r*t23i + t01i*t23r;
        float ar   = t03r*t45r - t03i*t45i,     ai   = t03r*t45i + t03i*t45r;

        #define GATE(L,Q) { \
            constexpr int MM = QM.M[L][Q]; \
            float br = xshuf<MM>(ar), bi = xshuf<MM>(ai); \
            float cg = cgv[(L)*6+(Q)], ss = ssin[(L)*6+(Q)]; \
            ar = cg*ar + ss*br; ai = cg*ai + ss*bi; }
        GATE(0,0) GATE(0,1) GATE(0,2) GATE(0,3) GATE(0,4) GATE(0,5)
        GATE(1,0) GATE(1,1) GATE(1,2) GATE(1,3) GATE(1,4) GATE(1,5)
        GATE(2,0) GATE(2,1) GATE(2,2) GATE(2,3) GATE(2,4) GATE(2,5)
        #undef GATE

        float wp = ar*ar + ai*ai;
        wp = wsgn[0]*wp + xshuf< 1>(wp);
        wp = wsgn[1]*wp + xshuf< 2>(wp);
        wp = wsgn[2]*wp + xshuf< 4>(wp);
        wp = wsgn[3]*wp + xshuf< 8>(wp);
        wp = wsgn[4]*wp + xshuf<16>(wp);
        wp = wsgn[5]*wp + xshuf<32>(wp);
        float ev0 = rdlane(wp, QM.R[0]), ev1 = rdlane(wp, QM.R[1]);
        float ev2 = rdlane(wp, QM.R[2]), ev3 = rdlane(wp, QM.R[3]);
        float ev4 = rdlane(wp, QM.R[4]), ev5 = rdlane(wp, QM.R[5]);

        float upd = bfcl + (wfcr[0]*ev0 + wfcr[1]*ev1)
                         + (wfcr[2]*ev2 + wfcr[3]*ev3)
                         + (wfcr[4]*ev4 + wfcr[5]*ev5);

        float hsel = hn;
        hsel = (lane == 0u) ? xnv : hsel;
        hsel = (lane == 1u) ? ynv : hsel;
        h = hsel + upd;
    }

    float pv = (lane < 32) ? h*woutl : 0.f;
    #pragma unroll
    for (int off = 32; off; off >>= 1) pv += __shfl_xor(pv, off, 64);
    if (lane == 0) out[b] = fsigmoid(pv + boutv);
}

extern "C" void kernel_launch(void* const* d_in, const int* in_sizes, int n_in,
                              void* d_out, int out_size, void* d_ws, size_t ws_size,
                              hipStream_t stream)
{
    (void)in_sizes; (void)n_in; (void)out_size;
    const float* x    = (const float*)d_in[0];
    const float* w0   = (const float*)d_in[1];
    const float* b0   = (const float*)d_in[2];
    const float* w1   = (const float*)d_in[3];
    const float* b1   = (const float*)d_in[4];
    const float* w2   = (const float*)d_in[5];
    const float* b2   = (const float*)d_in[6];
    const float* Wih  = (const float*)d_in[7];
    const float* Whh  = (const float*)d_in[8];
    const float* bih  = (const float*)d_in[9];
    const float* bhh  = (const float*)d_in[10];
    const float* qw   = (const float*)d_in[11];
    const float* Wfc  = (const float*)d_in[12];
    const float* bfc  = (const float*)d_in[13];
    const float* Wout = (const float*)d_in[14];
    const float* bout = (const float*)d_in[15];
    float* out = (float*)d_out;

    const size_t tensorN = (size_t)B_SIZE*HC*T_LEN;        // 8M floats = 32 MB
    float* t0 = (float*)d_ws;                              // (B,32,T)
    float* t1 = t0 + tensorN;                              // (B,32,T)
    float* tS = t0;                                        // (T,B,32), reuses t0
    float* G  = t1 + tensorN;                              // (T,B,128) = 134 MB
    const size_t need = (2*tensorN + (size_t)T_LEN*B_SIZE*128) * sizeof(float);

    conv0_kernel<<<2048, 256, 0, stream>>>(x, w0, b0, t0);
    convm_kernel<false><<<2048, 256, 0, stream>>>(t0, w1, b1, t1);
    convm_kernel<true ><<<2048, 256, 0, stream>>>(t1, w2, b2, tS);
    if (ws_size >= need){
        gates_kernel<<<(T_LEN*B_SIZE)/8, 256, 0, stream>>>(tS, Wih, bih, bhh, G);
        scan_kernel<<<256, 256, 0, stream>>>(G, Whh, qw, Wfc, bfc, Wout, bout, out);
    } else {
        scan_legacy<<<256, 256, 0, stream>>>(tS, Wih, Whh, bih, bhh, qw, Wfc, bfc, Wout, bout, out);
    }
}

// Round 7
// 660.406 us; speedup vs baseline: 1.1320x; 1.1320x over previous
//
#include <hip/hip_runtime.h>

#define B_SIZE 1024
#define T_LEN  256
#define D_IN   64
#define HC     32

typedef int   v2i_t __attribute__((ext_vector_type(2)));
typedef float v2f   __attribute__((ext_vector_type(2)));

__device__ __forceinline__ float frcp(float x){ return __builtin_amdgcn_rcpf(x); }
__device__ __forceinline__ float rfl(float x){
    return __uint_as_float(__builtin_amdgcn_readfirstlane(__float_as_uint(x)));
}
__device__ __forceinline__ float rdlane(float x, int l){
    return __int_as_float(__builtin_amdgcn_readlane(__float_as_int(x), l));
}
__device__ __forceinline__ float ftanh(float x){
    return 1.f - 2.f*frcp(__expf(2.f*x) + 1.f);
}
__device__ __forceinline__ float fsigmoid(float x){
    return frcp(1.f + __expf(-x));
}

template<int CTRL>
__device__ __forceinline__ int dppmov(int x){
    return __builtin_amdgcn_update_dpp(x, x, CTRL, 0xF, 0xF, false);
}

// xor within 16-lane rows, masks 1..15, pure DPP (1-2 ops)
template<int M>
__device__ __forceinline__ int dpp_xor(int x){
    static_assert(M >= 1 && M <= 15, "dpp_xor mask");
    constexpr int hi = M & 12;
    constexpr int q  = (hi == 4 || hi == 12) ? ((M & 3) ^ 3) : (M & 3);
    if constexpr (q == 1) x = dppmov<0xB1>(x);
    else if constexpr (q == 2) x = dppmov<0x4E>(x);
    else if constexpr (q == 3) x = dppmov<0x1B>(x);
    if constexpr (hi == 4)       x = dppmov<0x141>(x);   // ^7 -> with ^3 pre = ^4
    else if constexpr (hi == 8)  x = dppmov<0x128>(x);   // row_ror:8 = ^8
    else if constexpr (hi == 12) x = dppmov<0x140>(x);   // row_mirror = ^15
    return x;
}

#if defined(__has_builtin)
#  if __has_builtin(__builtin_amdgcn_permlane16_swap)
#    define HAVE_PL16 1
#  endif
#endif

// value of lane (lane ^ M) — fully VALU (R5/R6 HW-verified xor-trick for swaps)
template<int M>
__device__ __forceinline__ float xshuf(float xf){
    if constexpr (M == 0) return xf;
    int x = __float_as_int(xf);
    if constexpr (M & 15) x = dpp_xor<M & 15>(x);
    if constexpr (M & 16){
#ifdef HAVE_PL16
        v2i_t r = __builtin_amdgcn_permlane16_swap(x, x, false, false);
        x = r.x ^ r.y ^ x;
#else
        x = __builtin_amdgcn_ds_swizzle(x, (16 << 10) | 0x1F);
#endif
    }
    if constexpr (M & 32){
        v2i_t r = __builtin_amdgcn_permlane32_swap(x, x, false, false);
        x = r.x ^ r.y ^ x;
    }
    return __int_as_float(x);
}

// ---- compile-time GF(2) tracking of the CNOT-ring basis relabeling (R3-verified) ----
struct QMasks { int M[3][6]; int S[3][6]; int R[6]; };
constexpr QMasks qmasks(){
    QMasks qm{};
    unsigned m[6], n[6];
    for (int i = 0; i < 6; i++){ m[i] = 1u << i; n[i] = 1u << i; }
    for (int l = 0; l < 3; l++){
        for (int q = 0; q < 6; q++){
            unsigned u = m[q], r = 0;
            for (int i = 0; i < 6; i++) if ((u >> i) & 1u) r |= (32u >> i);
            qm.S[l][q] = (int)r;
            unsigned u2 = 0;
            for (int i = 0; i < 6; i++) u2 |= ((n[i] >> q) & 1u) << i;
            unsigned r2 = 0;
            for (int i = 0; i < 6; i++) if ((u2 >> i) & 1u) r2 |= (32u >> i);
            qm.M[l][q] = (int)r2;
        }
        for (int q = 0; q < 6; q++) m[(q + 1) % 6] ^= m[q];
        n[0] ^= n[5];
        for (int q = 4; q >= 0; q--) n[q + 1] ^= n[q];
    }
    for (int i = 0; i < 6; i++){
        unsigned u = m[i], r = 0;
        for (int j = 0; j < 6; j++) if ((u >> j) & 1u) r |= (32u >> j);
        qm.R[i] = (int)r;
    }
    return qm;
}
constexpr QMasks QM = qmasks();

// ---------------- conv0: x (B,T,64) -> t0 (B,32,T); coalesced weight staging ----------------
__global__ __launch_bounds__(256) void conv0_kernel(const float* __restrict__ x,
    const float* __restrict__ w0, const float* __restrict__ b0, float* __restrict__ out)
{
    __shared__ __align__(16) float xs[130*65];
    __shared__ __align__(16) float wl[192*36];   // [r=d*3+k][c], stride 36 (b128-aligned, conflict-free)
    const int tid = threadIdx.x;
    const int b  = blockIdx.x >> 1;
    const int s0 = (blockIdx.x & 1) * 128;

    for (int idx = tid; idx < 130*64; idx += 256){
        int r = idx >> 6, d = idx & 63;
        int s = s0 - 1 + r;
        float v = 0.f;
        if (s >= 0 && s < T_LEN) v = x[(size_t)b*(T_LEN*D_IN) + (size_t)s*D_IN + d];
        xs[r*65 + d] = v;
    }
    // coalesced global read, transposed LDS write
    for (int idx = tid; idx < 192*32; idx += 256){
        int c = idx / 192, r = idx - c*192;
        wl[r*36 + c] = w0[idx];
    }
    __syncthreads();

    const int c0 = (tid & 7) * 4;
    const int sl = (tid >> 3) * 4;
    float acc[4][4];
    #pragma unroll
    for (int ci = 0; ci < 4; ci++){
        float bb = b0[c0+ci];
        #pragma unroll
        for (int m = 0; m < 4; m++) acc[ci][m] = bb;
    }
    for (int d = 0; d < 64; d++){
        float xv[6];
        #pragma unroll
        for (int o = 0; o < 6; o++) xv[o] = xs[(sl+o)*65 + d];
        #pragma unroll
        for (int kk = 0; kk < 3; kk++){
            const float4 wv = *(const float4*)&wl[(d*3+kk)*36 + c0];
            float w4[4] = {wv.x, wv.y, wv.z, wv.w};
            #pragma unroll
            for (int ci = 0; ci < 4; ci++)
                #pragma unroll
                for (int m = 0; m < 4; m++)
                    acc[ci][m] += xv[m+kk]*w4[ci];
        }
    }
    #pragma unroll
    for (int ci = 0; ci < 4; ci++){
        float4 v;
        v.x = fmaxf(acc[ci][0], 0.f); v.y = fmaxf(acc[ci][1], 0.f);
        v.z = fmaxf(acc[ci][2], 0.f); v.w = fmaxf(acc[ci][3], 0.f);
        *(float4*)&out[(size_t)b*(HC*T_LEN) + (size_t)(c0+ci)*T_LEN + (s0+sl)] = v;
    }
}

// ------------- mid conv: (B,32,T) -> (B,32,T) or (T,B,32); coalesced weight staging -------------
template<bool TOUT>
__global__ __launch_bounds__(256) void convm_kernel(const float* __restrict__ in,
    const float* __restrict__ w, const float* __restrict__ bias, float* __restrict__ out)
{
    __shared__ __align__(16) float xs[130*33];
    __shared__ __align__(16) float wl[96*36];
    const int tid = threadIdx.x;
    const int b  = blockIdx.x >> 1;
    const int s0 = (blockIdx.x & 1) * 128;

    for (int idx = tid; idx < 32*130; idx += 256){
        int ci = idx / 130; int r = idx - ci*130;
        int s = s0 - 1 + r;
        float v = 0.f;
        if (s >= 0 && s < T_LEN) v = in[(size_t)b*(HC*T_LEN) + (size_t)ci*T_LEN + s];
        xs[r*33 + ci] = v;
    }
    for (int idx = tid; idx < 96*32; idx += 256){
        int c = idx / 96, r = idx - c*96;
        wl[r*36 + c] = w[idx];
    }
    __syncthreads();

    const int c0 = (tid & 7) * 4;
    const int sl = (tid >> 3) * 4;
    float acc[4][4];
    #pragma unroll
    for (int ci = 0; ci < 4; ci++){
        float bb = bias[c0+ci];
        #pragma unroll
        for (int m = 0; m < 4; m++) acc[ci][m] = bb;
    }
    for (int ci2 = 0; ci2 < 32; ci2++){
        float xv[6];
        #pragma unroll
        for (int o = 0; o < 6; o++) xv[o] = xs[(sl+o)*33 + ci2];
        #pragma unroll
        for (int kk = 0; kk < 3; kk++){
            const float4 wv = *(const float4*)&wl[(ci2*3+kk)*36 + c0];
            float w4[4] = {wv.x, wv.y, wv.z, wv.w};
            #pragma unroll
            for (int ci = 0; ci < 4; ci++)
                #pragma unroll
                for (int m = 0; m < 4; m++)
                    acc[ci][m] += xv[m+kk]*w4[ci];
        }
    }
    if (!TOUT){
        #pragma unroll
        for (int ci = 0; ci < 4; ci++){
            float4 v;
            v.x = fmaxf(acc[ci][0], 0.f); v.y = fmaxf(acc[ci][1], 0.f);
            v.z = fmaxf(acc[ci][2], 0.f); v.w = fmaxf(acc[ci][3], 0.f);
            *(float4*)&out[(size_t)b*(HC*T_LEN) + (size_t)(c0+ci)*T_LEN + (s0+sl)] = v;
        }
    } else {
        #pragma unroll
        for (int m = 0; m < 4; m++){
            int s = s0 + sl + m;
            float4 v;
            v.x = fmaxf(acc[0][m], 0.f); v.y = fmaxf(acc[1][m], 0.f);
            v.z = fmaxf(acc[2][m], 0.f); v.w = fmaxf(acc[3][m], 0.f);
            *(float4*)&out[(size_t)s*(B_SIZE*HC) + (size_t)b*HC + c0] = v;
        }
    }
}

// ------ fused conv2 + gates: in (B,32,T) -> G[(s*B+b)*128+r], no tS round-trip ------
// Phase 1: convm compute (identical math). Phase 2: tile -> LDS ts[s][36] (overlaid
// on dead xs/wl). Phase 3: per-thread gate-row GEMM, Wih rows in registers
// (amortized over 128 s), wave-uniform broadcast LDS reads, coalesced G stores.
__global__ __launch_bounds__(256) void convm_gates_kernel(const float* __restrict__ in,
    const float* __restrict__ w, const float* __restrict__ bias,
    const float* __restrict__ Wih, const float* __restrict__ bih,
    const float* __restrict__ bhh, float* __restrict__ G)
{
    __shared__ __align__(16) float smem[4292 + 3456];   // 31 KB
    float* xs = smem;            // [130][33] conv input tile
    float* wl = smem + 4292;     // [96][36]  transposed conv weights (16B-aligned base)
    float* ts = smem;            // [128][36] conv output tile (overlay; xs/wl dead)
    const int tid = threadIdx.x;
    const int b  = blockIdx.x >> 1;
    const int s0 = (blockIdx.x & 1) * 128;

    for (int idx = tid; idx < 32*130; idx += 256){
        int ci = idx / 130; int r = idx - ci*130;
        int s = s0 - 1 + r;
        float v = 0.f;
        if (s >= 0 && s < T_LEN) v = in[(size_t)b*(HC*T_LEN) + (size_t)ci*T_LEN + s];
        xs[r*33 + ci] = v;
    }
    for (int idx = tid; idx < 96*32; idx += 256){
        int c = idx / 96, r = idx - c*96;
        wl[r*36 + c] = w[idx];
    }
    __syncthreads();

    const int c0 = (tid & 7) * 4;
    const int sl = (tid >> 3) * 4;
    float acc[4][4];
    #pragma unroll
    for (int ci = 0; ci < 4; ci++){
        float bb = bias[c0+ci];
        #pragma unroll
        for (int m = 0; m < 4; m++) acc[ci][m] = bb;
    }
    for (int ci2 = 0; ci2 < 32; ci2++){
        float xv[6];
        #pragma unroll
        for (int o = 0; o < 6; o++) xv[o] = xs[(sl+o)*33 + ci2];
        #pragma unroll
        for (int kk = 0; kk < 3; kk++){
            const float4 wv = *(const float4*)&wl[(ci2*3+kk)*36 + c0];
            float w4[4] = {wv.x, wv.y, wv.z, wv.w};
            #pragma unroll
            for (int ci = 0; ci < 4; ci++)
                #pragma unroll
                for (int m = 0; m < 4; m++)
                    acc[ci][m] += xv[m+kk]*w4[ci];
        }
    }
    __syncthreads();   // all xs/wl reads complete before overlay write

    #pragma unroll
    for (int m = 0; m < 4; m++){
        float4 v;
        v.x = fmaxf(acc[0][m], 0.f); v.y = fmaxf(acc[1][m], 0.f);
        v.z = fmaxf(acc[2][m], 0.f); v.w = fmaxf(acc[3][m], 0.f);
        *(float4*)&ts[(sl+m)*36 + c0] = v;
    }
    __syncthreads();

    // ---- gate GEMM: thread = gate row r, halves interleave s ----
    const int r = tid & 127;
    const int half = tid >> 7;
    float4 wr[8];
    #pragma unroll
    for (int j4 = 0; j4 < 8; j4++) wr[j4] = ((const float4*)Wih)[r*8 + j4];
    const float br = bih[r] + bhh[r];

    for (int ss = half; ss < 128; ss += 2){
        float a0 = br, a1 = 0.f, a2 = 0.f, a3 = 0.f;
        #pragma unroll
        for (int j4 = 0; j4 < 8; j4++){
            const float4 xv = *(const float4*)&ts[ss*36 + j4*4];   // wave-uniform broadcast
            a0 += wr[j4].x*xv.x; a1 += wr[j4].y*xv.y;
            a2 += wr[j4].z*xv.z; a3 += wr[j4].w*xv.w;
        }
        G[((size_t)(s0+ss)*B_SIZE + b)*128 + r] = (a0+a1)+(a2+a3);
    }
}

// ------------- scan v3 (R6-proven): G-fed, DS-free inner loop, packed fp32 -------------
__global__ __launch_bounds__(256, 1) void scan_kernel(
    const float* __restrict__ G,   const float* __restrict__ Whh,
    const float* __restrict__ qw,  const float* __restrict__ Wfc,
    const float* __restrict__ bfc, const float* __restrict__ Wout,
    const float* __restrict__ bout, float* __restrict__ out)
{
    const unsigned lane = threadIdx.x & 63u;
    const int wv   = threadIdx.x >> 6;
    const int b    = __builtin_amdgcn_readfirstlane(blockIdx.x * 4 + wv);
    const int r1 = lane, r2 = lane + 64;       // gate rows: [i f | g o]
    const int k  = lane & 31;

    v2f uAB[32];
    #pragma unroll
    for (int j4 = 0; j4 < 8; j4++){
        float4 d_ = ((const float4*)Whh)[r1*8 + j4];
        float4 e  = ((const float4*)Whh)[r2*8 + j4];
        uAB[j4*4+0] = v2f{d_.x, e.x}; uAB[j4*4+1] = v2f{d_.y, e.y};
        uAB[j4*4+2] = v2f{d_.z, e.z}; uAB[j4*4+3] = v2f{d_.w, e.w};
    }

    float wfcr[6];
    #pragma unroll
    for (int j = 0; j < 6; j++) wfcr[j] = Wfc[k*6 + j];
    const float bfcl  = bfc[k];
    const float woutl = (lane < 32) ? Wout[k] : 0.f;
    const float boutv = bout[0];

    float cgv[18], ssin[18];
    #pragma unroll
    for (int g = 0; g < 18; g++){
        int l = g / 6, q = g % 6;
        float a = 0.5f * qw[g];
        float cv = __cosf(a), sv = __sinf(a);
        cgv[g] = rfl(cv);
        unsigned sm = (unsigned)QM.S[l][q];
        ssin[g] = (__builtin_popcount(sm & lane) & 1) ? sv : -sv;
    }
    float wsgn[6];
    #pragma unroll
    for (int j = 0; j < 6; j++) wsgn[j] = (lane & (1u << j)) ? -1.f : 1.f;
    const bool qs[6] = { (lane & 32u) != 0, (lane & 16u) != 0, (lane & 8u) != 0,
                         (lane & 4u) != 0,  (lane & 2u) != 0,  (lane & 1u) != 0 };

    float h = 0.f, c = 0.f;
    const float* gbase = G + (size_t)b*128;
    float g1 = gbase[r1], g2 = gbase[r2];

    #pragma clang loop unroll(disable)
    for (int s = 0; s < T_LEN; s++){
        const float cg1 = g1, cg2 = g2;
        {
            int s2 = (s + 1 < T_LEN) ? s + 1 : s;
            const float* gn = gbase + (size_t)s2*(B_SIZE*128);
            g1 = gn[r1]; g2 = gn[r2];
        }

        v2f a0 = v2f{cg1, cg2}, a1 = v2f{0.f,0.f}, a2 = v2f{0.f,0.f}, a3 = v2f{0.f,0.f};
        #pragma unroll
        for (int j = 0; j < 32; j += 4){
            float h0 = rdlane(h, j),   h1 = rdlane(h, j+1);
            float h2 = rdlane(h, j+2), h3 = rdlane(h, j+3);
            a0 += h0*uAB[j]; a1 += h1*uAB[j+1]; a2 += h2*uAB[j+2]; a3 += h3*uAB[j+3];
        }
        v2f accv = (a0+a1)+(a2+a3);
        float acc1 = accv.x, acc2 = accv.y;

        float sigA = fsigmoid(acc1);
        float argB = (lane < 32) ? acc2 : 0.5f*acc2;
        float tt   = ftanh(argB);
        float actB = (lane < 32) ? tt : (0.5f + 0.5f*tt);
        float fsig = xshuf<32>(sigA);
        float osig = xshuf<32>(actB);
        c = fsig*c + sigA*actB;
        float hn = osig * ftanh(c);

        hn = 3.99f * hn * (1.f - hn);
        float x0 = rdlane(hn, 0), y0 = rdlane(hn, 1);
        float xnv = 1.f - 1.4f*x0*x0 + y0;
        float ynv = 0.3f * x0;

        float ang[6];
        ang[0] = 0.5f*xnv; ang[1] = 0.5f*ynv;
        ang[2] = 0.5f*rdlane(hn, 2); ang[3] = 0.5f*rdlane(hn, 3);
        ang[4] = 0.5f*rdlane(hn, 4); ang[5] = 0.5f*rdlane(hn, 5);
        float ca[6], sa[6];
        #pragma unroll
        for (int j = 0; j < 6; j++){ ca[j] = __cosf(ang[j]); sa[j] = __sinf(ang[j]); }

        float fr[6], fi[6];
        #pragma unroll
        for (int i = 0; i < 6; i++){
            const int i1 = (i+1)%6, i2 = (i+2)%6;
            float cx=ca[i], sx=sa[i], cy=ca[i1], sy=sa[i1], cz=ca[i2], sz=sa[i2];
            float w0r = cy*cx, w0i = sy*sx;
            float w1r = sy*cx, w1i = -cy*sx;
            float q0r = cz*w0r + sz*w0i, q0i = cz*w0i - sz*w0r;
            float q1r = cz*w1r - sz*w1i, q1i = cz*w1i + sz*w1r;
            fr[i] = qs[i] ? q1r : q0r;
            fi[i] = qs[i] ? q1i : q0i;
        }
        v2f t01 = v2f{fr[0]*fr[1] - fi[0]*fi[1], fr[0]*fi[1] + fi[0]*fr[1]};
        v2f t23 = v2f{fr[2]*fr[3] - fi[2]*fi[3], fr[2]*fi[3] + fi[2]*fr[3]};
        v2f t45 = v2f{fr[4]*fr[5] - fi[4]*fi[5], fr[4]*fi[5] + fi[4]*fr[5]};
        v2f t03 = v2f{t01.x*t23.x - t01.y*t23.y, t01.x*t23.y + t01.y*t23.x};
        v2f av  = v2f{t03.x*t45.x - t03.y*t45.y, t03.x*t45.y + t03.y*t45.x};

        #define GATE(L,Q) { \
            constexpr int MM = QM.M[L][Q]; \
            v2f bv; bv.x = xshuf<MM>(av.x); bv.y = xshuf<MM>(av.y); \
            av = cgv[(L)*6+(Q)]*av + ssin[(L)*6+(Q)]*bv; }
        GATE(0,0) GATE(0,1) GATE(0,2) GATE(0,3) GATE(0,4) GATE(0,5)
        GATE(1,0) GATE(1,1) GATE(1,2) GATE(1,3) GATE(1,4) GATE(1,5)
        GATE(2,0) GATE(2,1) GATE(2,2) GATE(2,3) GATE(2,4) GATE(2,5)
        #undef GATE

        float wp = av.x*av.x + av.y*av.y;
        wp = wsgn[0]*wp + xshuf< 1>(wp);
        wp = wsgn[1]*wp + xshuf< 2>(wp);
        wp = wsgn[2]*wp + xshuf< 4>(wp);
        wp = wsgn[3]*wp + xshuf< 8>(wp);
        wp = wsgn[4]*wp + xshuf<16>(wp);
        wp = wsgn[5]*wp + xshuf<32>(wp);
        float ev0 = rdlane(wp, QM.R[0]), ev1 = rdlane(wp, QM.R[1]);
        float ev2 = rdlane(wp, QM.R[2]), ev3 = rdlane(wp, QM.R[3]);
        float ev4 = rdlane(wp, QM.R[4]), ev5 = rdlane(wp, QM.R[5]);

        float upd = bfcl + (wfcr[0]*ev0 + wfcr[1]*ev1)
                         + (wfcr[2]*ev2 + wfcr[3]*ev3)
                         + (wfcr[4]*ev4 + wfcr[5]*ev5);

        float hsel = hn;
        hsel = (lane == 0u) ? xnv : hsel;
        hsel = (lane == 1u) ? ynv : hsel;
        h = hsel + upd;
    }

    float pv = (lane < 32) ? h*woutl : 0.f;
    #pragma unroll
    for (int off = 32; off; off >>= 1) pv += __shfl_xor(pv, off, 64);
    if (lane == 0) out[b] = fsigmoid(pv + boutv);
}

// ---------------- legacy scan (R5-proven) — fallback if ws too small ----------------
__global__ __launch_bounds__(256, 1) void scan_legacy(
    const float* __restrict__ tS,
    const float* __restrict__ Wih, const float* __restrict__ Whh,
    const float* __restrict__ bih, const float* __restrict__ bhh,
    const float* __restrict__ qw,  const float* __restrict__ Wfc,
    const float* __restrict__ bfc, const float* __restrict__ Wout,
    const float* __restrict__ bout, float* __restrict__ out)
{
    const unsigned lane = threadIdx.x & 63u;
    const int wv   = threadIdx.x >> 6;
    const int b    = __builtin_amdgcn_readfirstlane(blockIdx.x * 4 + wv);
    const int r1 = lane, r2 = lane + 64;
    const int k  = lane & 31;

    float wA[32], wB[32], uA[32], uB[32];
    #pragma unroll
    for (int j4 = 0; j4 < 8; j4++){
        float4 a  = ((const float4*)Wih)[r1*8 + j4];
        float4 c_ = ((const float4*)Wih)[r2*8 + j4];
        float4 d_ = ((const float4*)Whh)[r1*8 + j4];
        float4 e  = ((const float4*)Whh)[r2*8 + j4];
        wA[j4*4+0]=a.x;  wA[j4*4+1]=a.y;  wA[j4*4+2]=a.z;  wA[j4*4+3]=a.w;
        wB[j4*4+0]=c_.x; wB[j4*4+1]=c_.y; wB[j4*4+2]=c_.z; wB[j4*4+3]=c_.w;
        uA[j4*4+0]=d_.x; uA[j4*4+1]=d_.y; uA[j4*4+2]=d_.z; uA[j4*4+3]=d_.w;
        uB[j4*4+0]=e.x;  uB[j4*4+1]=e.y;  uB[j4*4+2]=e.z;  uB[j4*4+3]=e.w;
    }
    const float bias1 = bih[r1] + bhh[r1];
    const float bias2 = bih[r2] + bhh[r2];

    float wfcr[6];
    #pragma unroll
    for (int j = 0; j < 6; j++) wfcr[j] = Wfc[k*6 + j];
    const float bfcl  = bfc[k];
    const float woutl = (lane < 32) ? Wout[k] : 0.f;
    const float boutv = bout[0];

    float cgv[18], ssin[18];
    #pragma unroll
    for (int g = 0; g < 18; g++){
        int l = g / 6, q = g % 6;
        float a = 0.5f * qw[g];
        float cv = __cosf(a), sv = __sinf(a);
        cgv[g] = rfl(cv);
        unsigned sm = (unsigned)QM.S[l][q];
        ssin[g] = (__builtin_popcount(sm & lane) & 1) ? sv : -sv;
    }
    float wsgn[6];
    #pragma unroll
    for (int j = 0; j < 6; j++) wsgn[j] = (lane & (1u << j)) ? -1.f : 1.f;
    const bool qs[6] = { (lane & 32u) != 0, (lane & 16u) != 0, (lane & 8u) != 0,
                         (lane & 4u) != 0,  (lane & 2u) != 0,  (lane & 1u) != 0 };

    float h = 0.f, c = 0.f;
    const float* xbase = tS + (size_t)b * HC;

    float4 xf[8];
    #pragma unroll
    for (int j4 = 0; j4 < 8; j4++) xf[j4] = ((const float4*)xbase)[j4];

    #pragma clang loop unroll(disable)
    for (int s = 0; s < T_LEN; s++){
        float xt[32];
        #pragma unroll
        for (int j4 = 0; j4 < 8; j4++){
            xt[j4*4+0]=xf[j4].x; xt[j4*4+1]=xf[j4].y; xt[j4*4+2]=xf[j4].z; xt[j4*4+3]=xf[j4].w;
        }
        {
            int s2 = (s + 1 < T_LEN) ? s + 1 : s;
            const float4* np_ = (const float4*)(xbase + (size_t)s2*(B_SIZE*HC));
            #pragma unroll
            for (int j4 = 0; j4 < 8; j4++) xf[j4] = np_[j4];
        }

        float a1a = bias1, a1b = 0.f, a2a = bias2, a2b = 0.f;
        #pragma unroll
        for (int j = 0; j < 32; j += 2){
            a1a += xt[j]*wA[j];     a1b += xt[j+1]*wA[j+1];
            a2a += xt[j]*wB[j];     a2b += xt[j+1]*wB[j+1];
        }
        #pragma unroll
        for (int j = 0; j < 32; j += 2){
            float h0 = rdlane(h, j), h1 = rdlane(h, j+1);
            a1a += h0*uA[j];   a1b += h1*uA[j+1];
            a2a += h0*uB[j];   a2b += h1*uB[j+1];
        }
        float acc1 = a1a + a1b, acc2 = a2a + a2b;

        float sigA = fsigmoid(acc1);
        float argB = (lane < 32) ? acc2 : 0.5f*acc2;
        float tt   = ftanh(argB);
        float actB = (lane < 32) ? tt : (0.5f + 0.5f*tt);
        float fsig = xshuf<32>(sigA);
        float osig = xshuf<32>(actB);
        c = fsig*c + sigA*actB;
        float hn = osig * ftanh(c);

        hn = 3.99f * hn * (1.f - hn);
        float x0 = rdlane(hn, 0), y0 = rdlane(hn, 1);
        float xnv = 1.f - 1.4f*x0*x0 + y0;
        float ynv = 0.3f * x0;

        float ang[6];
        ang[0] = 0.5f*xnv; ang[1] = 0.5f*ynv;
        ang[2] = 0.5f*rdlane(hn, 2); ang[3] = 0.5f*rdlane(hn, 3);
        ang[4] = 0.5f*rdlane(hn, 4); ang[5] = 0.5f*rdlane(hn, 5);
        float ca[6], sa[6];
        #pragma unroll
        for (int j = 0; j < 6; j++){ ca[j] = __cosf(ang[j]); sa[j] = __sinf(ang[j]); }

        float fr[6], fi[6];
        #pragma unroll
        for (int i = 0; i < 6; i++){
            const int i1 = (i+1)%6, i2 = (i+2)%6;
            float cx=ca[i], sx=sa[i], cy=ca[i1], sy=sa[i1], cz=ca[i2], sz=sa[i2];
            float w0r = cy*cx, w0i = sy*sx;
            float w1r = sy*cx, w1i = -cy*sx;
            float q0r = cz*w0r + sz*w0i, q0i = cz*w0i - sz*w0r;
            float q1r = cz*w1r - sz*w1i, q1i = cz*w1i + sz*w1r;
            fr[i] = qs[i] ? q1r : q0r;
            fi[i] = qs[i] ? q1i : q0i;
        }
        float t01r = fr[0]*fr[1] - fi[0]*fi[1], t01i = fr[0]*fi[1] + fi[0]*fr[1];
        float t23r = fr[2]*fr[3] - fi[2]*fi[3], t23i = fr[2]*fi[3] + fi[2]*fr[3];
        float t45r = fr[4]*fr[5] - fi[4]*fi[5], t45i = fr[4]*fi[5] + fi[4]*fr[5];
        float t03r = t01r*t23r - t01i*t23i,     t03i = t01r*t23i + t01i*t23r;
        float ar   = t03r*t45r - t03i*t45i,     ai   = t03r*t45i + t03i*t45r;

        #define GATE(L,Q) { \
            constexpr int MM = QM.M[L][Q]; \
            float br = xshuf<MM>(ar), bi = xshuf<MM>(ai); \
            float cg = cgv[(L)*6+(Q)], ss = ssin[(L)*6+(Q)]; \
            ar = cg*ar + ss*br; ai = cg*ai + ss*bi; }
        GATE(0,0) GATE(0,1) GATE(0,2) GATE(0,3) GATE(0,4) GATE(0,5)
        GATE(1,0) GATE(1,1) GATE(1,2) GATE(1,3) GATE(1,4) GATE(1,5)
        GATE(2,0) GATE(2,1) GATE(2,2) GATE(2,3) GATE(2,4) GATE(2,5)
        #undef GATE

        float wp = ar*ar + ai*ai;
        wp = wsgn[0]*wp + xshuf< 1>(wp);
        wp = wsgn[1]*wp + xshuf< 2>(wp);
        wp = wsgn[2]*wp + xshuf< 4>(wp);
        wp = wsgn[3]*wp + xshuf< 8>(wp);
        wp = wsgn[4]*wp + xshuf<16>(wp);
        wp = wsgn[5]*wp + xshuf<32>(wp);
        float ev0 = rdlane(wp, QM.R[0]), ev1 = rdlane(wp, QM.R[1]);
        float ev2 = rdlane(wp, QM.R[2]), ev3 = rdlane(wp, QM.R[3]);
        float ev4 = rdlane(wp, QM.R[4]), ev5 = rdlane(wp, QM.R[5]);

        float upd = bfcl + (wfcr[0]*ev0 + wfcr[1]*ev1)
                         + (wfcr[2]*ev2 + wfcr[3]*ev3)
                         + (wfcr[4]*ev4 + wfcr[5]*ev5);

        float hsel = hn;
        hsel = (lane == 0u) ? xnv : hsel;
        hsel = (lane == 1u) ? ynv : hsel;
        h = hsel + upd;
    }

    float pv = (lane < 32) ? h*woutl : 0.f;
    #pragma unroll
    for (int off = 32; off; off >>= 1) pv += __shfl_xor(pv, off, 64);
    if (lane == 0) out[b] = fsigmoid(pv + boutv);
}

extern "C" void kernel_launch(void* const* d_in, const int* in_sizes, int n_in,
                              void* d_out, int out_size, void* d_ws, size_t ws_size,
                              hipStream_t stream)
{
    (void)in_sizes; (void)n_in; (void)out_size;
    const float* x    = (const float*)d_in[0];
    const float* w0   = (const float*)d_in[1];
    const float* b0   = (const float*)d_in[2];
    const float* w1   = (const float*)d_in[3];
    const float* b1   = (const float*)d_in[4];
    const float* w2   = (const float*)d_in[5];
    const float* b2   = (const float*)d_in[6];
    const float* Wih  = (const float*)d_in[7];
    const float* Whh  = (const float*)d_in[8];
    const float* bih  = (const float*)d_in[9];
    const float* bhh  = (const float*)d_in[10];
    const float* qw   = (const float*)d_in[11];
    const float* Wfc  = (const float*)d_in[12];
    const float* bfc  = (const float*)d_in[13];
    const float* Wout = (const float*)d_in[14];
    const float* bout = (const float*)d_in[15];
    float* out = (float*)d_out;

    const size_t tensorN = (size_t)B_SIZE*HC*T_LEN;        // 8M floats = 32 MB
    float* t0 = (float*)d_ws;                              // (B,32,T)
    float* t1 = t0 + tensorN;                              // (B,32,T)
    float* G  = t1 + tensorN;                              // (T,B,128) = 134 MB
    const size_t need = (2*tensorN + (size_t)T_LEN*B_SIZE*128) * sizeof(float);

    conv0_kernel<<<2048, 256, 0, stream>>>(x, w0, b0, t0);
    convm_kernel<false><<<2048, 256, 0, stream>>>(t0, w1, b1, t1);
    if (ws_size >= need){
        convm_gates_kernel<<<2048, 256, 0, stream>>>(t1, w2, b2, Wih, bih, bhh, G);
        scan_kernel<<<256, 256, 0, stream>>>(G, Whh, qw, Wfc, bfc, Wout, bout, out);
    } else {
        float* tS = t0;                                    // (T,B,32), reuses t0
        convm_kernel<true ><<<2048, 256, 0, stream>>>(t1, w2, b2, tS);
        scan_legacy<<<256, 256, 0, stream>>>(tS, Wih, Whh, bih, bhh, qw, Wfc, bfc, Wout, bout, out);
    }
}

// Round 9
// 636.612 us; speedup vs baseline: 1.1743x; 1.0374x over previous
//
#include <hip/hip_runtime.h>

#define B_SIZE 1024
#define T_LEN  256
#define D_IN   64
#define HC     32

typedef int   v2i_t __attribute__((ext_vector_type(2)));
typedef float v2f   __attribute__((ext_vector_type(2)));

__device__ __forceinline__ float frcp(float x){ return __builtin_amdgcn_rcpf(x); }
__device__ __forceinline__ float rfl(float x){
    return __uint_as_float(__builtin_amdgcn_readfirstlane(__float_as_uint(x)));
}
__device__ __forceinline__ float rdlane(float x, int l){
    return __int_as_float(__builtin_amdgcn_readlane(__float_as_int(x), l));
}
__device__ __forceinline__ float ftanh(float x){
    return 1.f - 2.f*frcp(__expf(2.f*x) + 1.f);
}
__device__ __forceinline__ float fsigmoid(float x){
    return frcp(1.f + __expf(-x));
}

template<int CTRL>
__device__ __forceinline__ int dppmov(int x){
    return __builtin_amdgcn_update_dpp(x, x, CTRL, 0xF, 0xF, false);
}

// xor within 16-lane rows, masks 1..15, pure DPP (1-2 ops)
template<int M>
__device__ __forceinline__ int dpp_xor(int x){
    static_assert(M >= 1 && M <= 15, "dpp_xor mask");
    constexpr int hi = M & 12;
    constexpr int q  = (hi == 4 || hi == 12) ? ((M & 3) ^ 3) : (M & 3);
    if constexpr (q == 1) x = dppmov<0xB1>(x);
    else if constexpr (q == 2) x = dppmov<0x4E>(x);
    else if constexpr (q == 3) x = dppmov<0x1B>(x);
    if constexpr (hi == 4)       x = dppmov<0x141>(x);   // ^7 -> with ^3 pre = ^4
    else if constexpr (hi == 8)  x = dppmov<0x128>(x);   // row_ror:8 = ^8
    else if constexpr (hi == 12) x = dppmov<0x140>(x);   // row_mirror = ^15
    return x;
}

#if defined(__has_builtin)
#  if __has_builtin(__builtin_amdgcn_permlane16_swap)
#    define HAVE_PL16 1
#  endif
#endif

// value of lane (lane ^ M) — fully VALU (R5/R6 HW-verified xor-trick for swaps)
template<int M>
__device__ __forceinline__ float xshuf(float xf){
    if constexpr (M == 0) return xf;
    int x = __float_as_int(xf);
    if constexpr (M & 15) x = dpp_xor<M & 15>(x);
    if constexpr (M & 16){
#ifdef HAVE_PL16
        v2i_t r = __builtin_amdgcn_permlane16_swap(x, x, false, false);
        x = r.x ^ r.y ^ x;
#else
        x = __builtin_amdgcn_ds_swizzle(x, (16 << 10) | 0x1F);
#endif
    }
    if constexpr (M & 32){
        v2i_t r = __builtin_amdgcn_permlane32_swap(x, x, false, false);
        x = r.x ^ r.y ^ x;
    }
    return __int_as_float(x);
}

// ---- compile-time GF(2) tracking of the CNOT-ring basis relabeling (R3-verified) ----
struct QMasks { int M[3][6]; int S[3][6]; int R[6]; };
constexpr QMasks qmasks(){
    QMasks qm{};
    unsigned m[6], n[6];
    for (int i = 0; i < 6; i++){ m[i] = 1u << i; n[i] = 1u << i; }
    for (int l = 0; l < 3; l++){
        for (int q = 0; q < 6; q++){
            unsigned u = m[q], r = 0;
            for (int i = 0; i < 6; i++) if ((u >> i) & 1u) r |= (32u >> i);
            qm.S[l][q] = (int)r;
            unsigned u2 = 0;
            for (int i = 0; i < 6; i++) u2 |= ((n[i] >> q) & 1u) << i;
            unsigned r2 = 0;
            for (int i = 0; i < 6; i++) if ((u2 >> i) & 1u) r2 |= (32u >> i);
            qm.M[l][q] = (int)r2;
        }
        for (int q = 0; q < 6; q++) m[(q + 1) % 6] ^= m[q];
        n[0] ^= n[5];
        for (int q = 4; q >= 0; q--) n[q + 1] ^= n[q];
    }
    for (int i = 0; i < 6; i++){
        unsigned u = m[i], r = 0;
        for (int j = 0; j < 6; j++) if ((u >> j) & 1u) r |= (32u >> j);
        qm.R[i] = (int)r;
    }
    return qm;
}
constexpr QMasks QM = qmasks();

// -------- conv0: x (B,T,64) -> t0 (B,32,T); split-d staging for 3 blocks/CU --------
__global__ __launch_bounds__(256) void conv0_kernel(const float* __restrict__ x,
    const float* __restrict__ w0, const float* __restrict__ b0, float* __restrict__ out)
{
    __shared__ float xs[130*33];                 // half-d tile (d 0..31 or 32..63)
    __shared__ __align__(16) float wl[192*36];   // [r=d*3+k][c]
    const int tid = threadIdx.x;
    const int b  = blockIdx.x >> 1;
    const int s0 = (blockIdx.x & 1) * 128;

    for (int idx = tid; idx < 192*32; idx += 256){
        int c = idx / 192, r = idx - c*192;
        wl[r*36 + c] = w0[idx];
    }

    const int c0 = (tid & 7) * 4;
    const int sl = (tid >> 3) * 4;
    float acc[4][4];
    #pragma unroll
    for (int ci = 0; ci < 4; ci++){
        float bb = b0[c0+ci];
        #pragma unroll
        for (int m = 0; m < 4; m++) acc[ci][m] = bb;
    }

    for (int half = 0; half < 2; half++){
        __syncthreads();    // 1st: wl staged; 2nd: previous half's xs reads done
        for (int idx = tid; idx < 130*32; idx += 256){
            int r = idx >> 5, d = idx & 31;
            int s = s0 - 1 + r;
            float v = 0.f;
            if (s >= 0 && s < T_LEN) v = x[(size_t)b*(T_LEN*D_IN) + (size_t)s*D_IN + half*32 + d];
            xs[r*33 + d] = v;
        }
        __syncthreads();
        for (int d = 0; d < 32; d++){
            float xv[6];
            #pragma unroll
            for (int o = 0; o < 6; o++) xv[o] = xs[(sl+o)*33 + d];
            const int dd = half*32 + d;
            #pragma unroll
            for (int kk = 0; kk < 3; kk++){
                const float4 wv = *(const float4*)&wl[(dd*3+kk)*36 + c0];
                float w4[4] = {wv.x, wv.y, wv.z, wv.w};
                #pragma unroll
                for (int ci = 0; ci < 4; ci++)
                    #pragma unroll
                    for (int m = 0; m < 4; m++)
                        acc[ci][m] += xv[m+kk]*w4[ci];
            }
        }
    }
    #pragma unroll
    for (int ci = 0; ci < 4; ci++){
        float4 v;
        v.x = fmaxf(acc[ci][0], 0.f); v.y = fmaxf(acc[ci][1], 0.f);
        v.z = fmaxf(acc[ci][2], 0.f); v.w = fmaxf(acc[ci][3], 0.f);
        *(float4*)&out[(size_t)b*(HC*T_LEN) + (size_t)(c0+ci)*T_LEN + (s0+sl)] = v;
    }
}

// ----- fused conv1 + conv2 + gates: t0 (B,32,T) -> G[(s*B+b)*128+r], all in-LDS -----
// FIX vs R8: t1t rows at absolute s<0 or s>=T are ZERO (conv2's input padding),
// not conv1 evaluated at the padded position.
__global__ __launch_bounds__(256) void conv12g_kernel(const float* __restrict__ t0g,
    const float* __restrict__ w1, const float* __restrict__ b1,
    const float* __restrict__ w2, const float* __restrict__ b2,
    const float* __restrict__ Wih, const float* __restrict__ bih,
    const float* __restrict__ bhh, float* __restrict__ G)
{
    __shared__ __align__(16) float smem[4608 + 3456 + 4290];  // 49.4 KB
    float* t0t = smem;                 // [132][33]  (4356 used of 4608)
    float* t2t = smem;                 // [128][36]  overlays t0t region (4608)
    float* wlr = smem + 4608;          // [96][36]   w1 then w2
    float* t1t = smem + 4608 + 3456;   // [130][33]
    const int tid = threadIdx.x;
    const int b  = blockIdx.x >> 1;
    const int s0 = (blockIdx.x & 1) * 128;

    // ---- stage t0 tile (rows s0-2 .. s0+129) + w1 ----
    for (int idx = tid; idx < 132*32; idx += 256){
        int ci = idx / 132, r = idx - ci*132;
        int s = s0 - 2 + r;
        float v = 0.f;
        if (s >= 0 && s < T_LEN) v = t0g[(size_t)b*(HC*T_LEN) + (size_t)ci*T_LEN + s];
        t0t[r*33 + ci] = v;
    }
    for (int idx = tid; idx < 96*32; idx += 256){
        int c = idx / 96, r = idx - c*96;
        wlr[r*36 + c] = w1[idx];
    }
    __syncthreads();

    // ---- phase 1: conv1, 130 output rows; groups 30,31 take 5 rows each ----
    const int c0 = (tid & 7) * 4;
    const int g  = tid >> 3;
    const int base1 = (g < 30) ? 4*g : (120 + 5*(g - 30));
    const int nr1   = (g < 30) ? 4 : 5;
    {
        float acc[4][5];
        #pragma unroll
        for (int ci = 0; ci < 4; ci++){
            float bb = b1[c0+ci];
            #pragma unroll
            for (int m = 0; m < 5; m++) acc[ci][m] = bb;
        }
        for (int ci2 = 0; ci2 < 32; ci2++){
            float xv[7];
            #pragma unroll
            for (int o = 0; o < 7; o++) xv[o] = t0t[(base1+o)*33 + ci2];
            #pragma unroll
            for (int kk = 0; kk < 3; kk++){
                const float4 wv = *(const float4*)&wlr[(ci2*3+kk)*36 + c0];
                float w4[4] = {wv.x, wv.y, wv.z, wv.w};
                #pragma unroll
                for (int ci = 0; ci < 4; ci++)
                    #pragma unroll
                    for (int m = 0; m < 5; m++)
                        acc[ci][m] += xv[m+kk]*w4[ci];
            }
        }
        // write t1t; rows at absolute s outside [0,T) are conv2 padding -> 0
        #pragma unroll
        for (int m = 0; m < 5; m++){
            if (m < nr1){
                const int rt = base1 + m;
                const int s_act = s0 - 1 + rt;
                const bool inb = (s_act >= 0) && (s_act < T_LEN);
                #pragma unroll
                for (int ci = 0; ci < 4; ci++)
                    t1t[rt*33 + c0 + ci] = inb ? fmaxf(acc[ci][m], 0.f) : 0.f;
            }
        }
    }
    __syncthreads();   // conv1 reads of t0t/wlr done; t1t written

    // ---- stage w2 (overwrites w1 region) ----
    for (int idx = tid; idx < 96*32; idx += 256){
        int c = idx / 96, r = idx - c*96;
        wlr[r*36 + c] = w2[idx];
    }
    __syncthreads();

    // ---- phase 2: conv2, 128 output rows into t2t (overlays t0t) ----
    const int base2 = 4*g;
    {
        float acc[4][4];
        #pragma unroll
        for (int ci = 0; ci < 4; ci++){
            float bb = b2[c0+ci];
            #pragma unroll
            for (int m = 0; m < 4; m++) acc[ci][m] = bb;
        }
        for (int ci2 = 0; ci2 < 32; ci2++){
            float xv[6];
            #pragma unroll
            for (int o = 0; o < 6; o++) xv[o] = t1t[(base2+o)*33 + ci2];
            #pragma unroll
            for (int kk = 0; kk < 3; kk++){
                const float4 wv = *(const float4*)&wlr[(ci2*3+kk)*36 + c0];
                float w4[4] = {wv.x, wv.y, wv.z, wv.w};
                #pragma unroll
                for (int ci = 0; ci < 4; ci++)
                    #pragma unroll
                    for (int m = 0; m < 4; m++)
                        acc[ci][m] += xv[m+kk]*w4[ci];
            }
        }
        __syncthreads();   // t0t region reads fully done before overlay write
        #pragma unroll
        for (int m = 0; m < 4; m++){
            float4 v;
            v.x = fmaxf(acc[0][m], 0.f); v.y = fmaxf(acc[1][m], 0.f);
            v.z = fmaxf(acc[2][m], 0.f); v.w = fmaxf(acc[3][m], 0.f);
            *(float4*)&t2t[(base2+m)*36 + c0] = v;
        }
    }
    __syncthreads();

    // ---- phase 3: gates GEMM, lane r handles gate rows r and r+64 ----
    const int r = tid & 63;
    const int wvv = tid >> 6;
    float4 wrA[8], wrB[8];
    #pragma unroll
    for (int j4 = 0; j4 < 8; j4++){
        wrA[j4] = ((const float4*)Wih)[r*8 + j4];
        wrB[j4] = ((const float4*)Wih)[(r+64)*8 + j4];
    }
    const float brA = bih[r]    + bhh[r];
    const float brB = bih[r+64] + bhh[r+64];

    for (int ss = wvv; ss < 128; ss += 4){
        float a0 = brA, a1 = 0.f, a2 = 0.f, a3 = 0.f;
        float e0 = brB, e1 = 0.f, e2 = 0.f, e3 = 0.f;
        #pragma unroll
        for (int j4 = 0; j4 < 8; j4++){
            const float4 xv = *(const float4*)&t2t[ss*36 + j4*4];   // wave-uniform broadcast
            a0 += wrA[j4].x*xv.x; a1 += wrA[j4].y*xv.y;
            a2 += wrA[j4].z*xv.z; a3 += wrA[j4].w*xv.w;
            e0 += wrB[j4].x*xv.x; e1 += wrB[j4].y*xv.y;
            e2 += wrB[j4].z*xv.z; e3 += wrB[j4].w*xv.w;
        }
        const size_t gi = ((size_t)(s0+ss)*B_SIZE + b)*128 + r;
        G[gi]      = (a0+a1)+(a2+a3);
        G[gi + 64] = (e0+e1)+(e2+e3);
    }
}

// ------------- mid conv (fallback only): (B,32,T) -> (B,32,T) or (T,B,32) -------------
template<bool TOUT>
__global__ __launch_bounds__(256) void convm_kernel(const float* __restrict__ in,
    const float* __restrict__ w, const float* __restrict__ bias, float* __restrict__ out)
{
    __shared__ __align__(16) float xs[130*33];
    __shared__ __align__(16) float wl[96*36];
    const int tid = threadIdx.x;
    const int b  = blockIdx.x >> 1;
    const int s0 = (blockIdx.x & 1) * 128;

    for (int idx = tid; idx < 32*130; idx += 256){
        int ci = idx / 130; int r = idx - ci*130;
        int s = s0 - 1 + r;
        float v = 0.f;
        if (s >= 0 && s < T_LEN) v = in[(size_t)b*(HC*T_LEN) + (size_t)ci*T_LEN + s];
        xs[r*33 + ci] = v;
    }
    for (int idx = tid; idx < 96*32; idx += 256){
        int c = idx / 96, r = idx - c*96;
        wl[r*36 + c] = w[idx];
    }
    __syncthreads();

    const int c0 = (tid & 7) * 4;
    const int sl = (tid >> 3) * 4;
    float acc[4][4];
    #pragma unroll
    for (int ci = 0; ci < 4; ci++){
        float bb = bias[c0+ci];
        #pragma unroll
        for (int m = 0; m < 4; m++) acc[ci][m] = bb;
    }
    for (int ci2 = 0; ci2 < 32; ci2++){
        float xv[6];
        #pragma unroll
        for (int o = 0; o < 6; o++) xv[o] = xs[(sl+o)*33 + ci2];
        #pragma unroll
        for (int kk = 0; kk < 3; kk++){
            const float4 wv = *(const float4*)&wl[(ci2*3+kk)*36 + c0];
            float w4[4] = {wv.x, wv.y, wv.z, wv.w};
            #pragma unroll
            for (int ci = 0; ci < 4; ci++)
                #pragma unroll
                for (int m = 0; m < 4; m++)
                    acc[ci][m] += xv[m+kk]*w4[ci];
        }
    }
    if (!TOUT){
        #pragma unroll
        for (int ci = 0; ci < 4; ci++){
            float4 v;
            v.x = fmaxf(acc[ci][0], 0.f); v.y = fmaxf(acc[ci][1], 0.f);
            v.z = fmaxf(acc[ci][2], 0.f); v.w = fmaxf(acc[ci][3], 0.f);
            *(float4*)&out[(size_t)b*(HC*T_LEN) + (size_t)(c0+ci)*T_LEN + (s0+sl)] = v;
        }
    } else {
        #pragma unroll
        for (int m = 0; m < 4; m++){
            int s = s0 + sl + m;
            float4 v;
            v.x = fmaxf(acc[0][m], 0.f); v.y = fmaxf(acc[1][m], 0.f);
            v.z = fmaxf(acc[2][m], 0.f); v.w = fmaxf(acc[3][m], 0.f);
            *(float4*)&out[(size_t)s*(B_SIZE*HC) + (size_t)b*HC + c0] = v;
        }
    }
}

// ------------- scan v3 (R6/R7-proven): G-fed, DS-free inner loop, packed fp32 -------------
__global__ __launch_bounds__(256, 1) void scan_kernel(
    const float* __restrict__ G,   const float* __restrict__ Whh,
    const float* __restrict__ qw,  const float* __restrict__ Wfc,
    const float* __restrict__ bfc, const float* __restrict__ Wout,
    const float* __restrict__ bout, float* __restrict__ out)
{
    const unsigned lane = threadIdx.x & 63u;
    const int wv   = threadIdx.x >> 6;
    const int b    = __builtin_amdgcn_readfirstlane(blockIdx.x * 4 + wv);
    const int r1 = lane, r2 = lane + 64;       // gate rows: [i f | g o]
    const int k  = lane & 31;

    v2f uAB[32];
    #pragma unroll
    for (int j4 = 0; j4 < 8; j4++){
        float4 d_ = ((const float4*)Whh)[r1*8 + j4];
        float4 e  = ((const float4*)Whh)[r2*8 + j4];
        uAB[j4*4+0] = v2f{d_.x, e.x}; uAB[j4*4+1] = v2f{d_.y, e.y};
        uAB[j4*4+2] = v2f{d_.z, e.z}; uAB[j4*4+3] = v2f{d_.w, e.w};
    }

    float wfcr[6];
    #pragma unroll
    for (int j = 0; j < 6; j++) wfcr[j] = Wfc[k*6 + j];
    const float bfcl  = bfc[k];
    const float woutl = (lane < 32) ? Wout[k] : 0.f;
    const float boutv = bout[0];

    float cgv[18], ssin[18];
    #pragma unroll
    for (int g = 0; g < 18; g++){
        int l = g / 6, q = g % 6;
        float a = 0.5f * qw[g];
        float cv = __cosf(a), sv = __sinf(a);
        cgv[g] = rfl(cv);
        unsigned sm = (unsigned)QM.S[l][q];
        ssin[g] = (__builtin_popcount(sm & lane) & 1) ? sv : -sv;
    }
    float wsgn[6];
    #pragma unroll
    for (int j = 0; j < 6; j++) wsgn[j] = (lane & (1u << j)) ? -1.f : 1.f;
    const bool qs[6] = { (lane & 32u) != 0, (lane & 16u) != 0, (lane & 8u) != 0,
                         (lane & 4u) != 0,  (lane & 2u) != 0,  (lane & 1u) != 0 };

    float h = 0.f, c = 0.f;
    const float* gbase = G + (size_t)b*128;
    float g1 = gbase[r1], g2 = gbase[r2];

    #pragma clang loop unroll(disable)
    for (int s = 0; s < T_LEN; s++){
        const float cg1 = g1, cg2 = g2;
        {
            int s2 = (s + 1 < T_LEN) ? s + 1 : s;
            const float* gn = gbase + (size_t)s2*(B_SIZE*128);
            g1 = gn[r1]; g2 = gn[r2];
        }

        v2f a0 = v2f{cg1, cg2}, a1 = v2f{0.f,0.f}, a2 = v2f{0.f,0.f}, a3 = v2f{0.f,0.f};
        #pragma unroll
        for (int j = 0; j < 32; j += 4){
            float h0 = rdlane(h, j),   h1 = rdlane(h, j+1);
            float h2 = rdlane(h, j+2), h3 = rdlane(h, j+3);
            a0 += h0*uAB[j]; a1 += h1*uAB[j+1]; a2 += h2*uAB[j+2]; a3 += h3*uAB[j+3];
        }
        v2f accv = (a0+a1)+(a2+a3);
        float acc1 = accv.x, acc2 = accv.y;

        float sigA = fsigmoid(acc1);
        float argB = (lane < 32) ? acc2 : 0.5f*acc2;
        float tt   = ftanh(argB);
        float actB = (lane < 32) ? tt : (0.5f + 0.5f*tt);
        float fsig = xshuf<32>(sigA);
        float osig = xshuf<32>(actB);
        c = fsig*c + sigA*actB;
        float hn = osig * ftanh(c);

        hn = 3.99f * hn * (1.f - hn);
        float x0 = rdlane(hn, 0), y0 = rdlane(hn, 1);
        float xnv = 1.f - 1.4f*x0*x0 + y0;
        float ynv = 0.3f * x0;

        float ang[6];
        ang[0] = 0.5f*xnv; ang[1] = 0.5f*ynv;
        ang[2] = 0.5f*rdlane(hn, 2); ang[3] = 0.5f*rdlane(hn, 3);
        ang[4] = 0.5f*rdlane(hn, 4); ang[5] = 0.5f*rdlane(hn, 5);
        float ca[6], sa[6];
        #pragma unroll
        for (int j = 0; j < 6; j++){ ca[j] = __cosf(ang[j]); sa[j] = __sinf(ang[j]); }

        float fr[6], fi[6];
        #pragma unroll
        for (int i = 0; i < 6; i++){
            const int i1 = (i+1)%6, i2 = (i+2)%6;
            float cx=ca[i], sx=sa[i], cy=ca[i1], sy=sa[i1], cz=ca[i2], sz=sa[i2];
            float w0r = cy*cx, w0i = sy*sx;
            float w1r = sy*cx, w1i = -cy*sx;
            float q0r = cz*w0r + sz*w0i, q0i = cz*w0i - sz*w0r;
            float q1r = cz*w1r - sz*w1i, q1i = cz*w1i + sz*w1r;
            fr[i] = qs[i] ? q1r : q0r;
            fi[i] = qs[i] ? q1i : q0i;
        }
        v2f t01 = v2f{fr[0]*fr[1] - fi[0]*fi[1], fr[0]*fi[1] + fi[0]*fr[1]};
        v2f t23 = v2f{fr[2]*fr[3] - fi[2]*fi[3], fr[2]*fi[3] + fi[2]*fr[3]};
        v2f t45 = v2f{fr[4]*fr[5] - fi[4]*fi[5], fr[4]*fi[5] + fi[4]*fr[5]};
        v2f t03 = v2f{t01.x*t23.x - t01.y*t23.y, t01.x*t23.y + t01.y*t23.x};
        v2f av  = v2f{t03.x*t45.x - t03.y*t45.y, t03.x*t45.y + t03.y*t45.x};

        #define GATE(L,Q) { \
            constexpr int MM = QM.M[L][Q]; \
            v2f bv; bv.x = xshuf<MM>(av.x); bv.y = xshuf<MM>(av.y); \
            av = cgv[(L)*6+(Q)]*av + ssin[(L)*6+(Q)]*bv; }
        GATE(0,0) GATE(0,1) GATE(0,2) GATE(0,3) GATE(0,4) GATE(0,5)
        GATE(1,0) GATE(1,1) GATE(1,2) GATE(1,3) GATE(1,4) GATE(1,5)
        GATE(2,0) GATE(2,1) GATE(2,2) GATE(2,3) GATE(2,4) GATE(2,5)
        #undef GATE

        float wp = av.x*av.x + av.y*av.y;
        wp = wsgn[0]*wp + xshuf< 1>(wp);
        wp = wsgn[1]*wp + xshuf< 2>(wp);
        wp = wsgn[2]*wp + xshuf< 4>(wp);
        wp = wsgn[3]*wp + xshuf< 8>(wp);
        wp = wsgn[4]*wp + xshuf<16>(wp);
        wp = wsgn[5]*wp + xshuf<32>(wp);
        float ev0 = rdlane(wp, QM.R[0]), ev1 = rdlane(wp, QM.R[1]);
        float ev2 = rdlane(wp, QM.R[2]), ev3 = rdlane(wp, QM.R[3]);
        float ev4 = rdlane(wp, QM.R[4]), ev5 = rdlane(wp, QM.R[5]);

        float upd = bfcl + (wfcr[0]*ev0 + wfcr[1]*ev1)
                         + (wfcr[2]*ev2 + wfcr[3]*ev3)
                         + (wfcr[4]*ev4 + wfcr[5]*ev5);

        float hsel = hn;
        hsel = (lane == 0u) ? xnv : hsel;
        hsel = (lane == 1u) ? ynv : hsel;
        h = hsel + upd;
    }

    float pv = (lane < 32) ? h*woutl : 0.f;
    #pragma unroll
    for (int off = 32; off; off >>= 1) pv += __shfl_xor(pv, off, 64);
    if (lane == 0) out[b] = fsigmoid(pv + boutv);
}

// ---------------- legacy scan (R5-proven) — fallback if ws too small ----------------
__global__ __launch_bounds__(256, 1) void scan_legacy(
    const float* __restrict__ tS,
    const float* __restrict__ Wih, const float* __restrict__ Whh,
    const float* __restrict__ bih, const float* __restrict__ bhh,
    const float* __restrict__ qw,  const float* __restrict__ Wfc,
    const float* __restrict__ bfc, const float* __restrict__ Wout,
    const float* __restrict__ bout, float* __restrict__ out)
{
    const unsigned lane = threadIdx.x & 63u;
    const int wv   = threadIdx.x >> 6;
    const int b    = __builtin_amdgcn_readfirstlane(blockIdx.x * 4 + wv);
    const int r1 = lane, r2 = lane + 64;
    const int k  = lane & 31;

    float wA[32], wB[32], uA[32], uB[32];
    #pragma unroll
    for (int j4 = 0; j4 < 8; j4++){
        float4 a  = ((const float4*)Wih)[r1*8 + j4];
        float4 c_ = ((const float4*)Wih)[r2*8 + j4];
        float4 d_ = ((const float4*)Whh)[r1*8 + j4];
        float4 e  = ((const float4*)Whh)[r2*8 + j4];
        wA[j4*4+0]=a.x;  wA[j4*4+1]=a.y;  wA[j4*4+2]=a.z;  wA[j4*4+3]=a.w;
        wB[j4*4+0]=c_.x; wB[j4*4+1]=c_.y; wB[j4*4+2]=c_.z; wB[j4*4+3]=c_.w;
        uA[j4*4+0]=d_.x; uA[j4*4+1]=d_.y; uA[j4*4+2]=d_.z; uA[j4*4+3]=d_.w;
        uB[j4*4+0]=e.x;  uB[j4*4+1]=e.y;  uB[j4*4+2]=e.z;  uB[j4*4+3]=e.w;
    }
    const float bias1 = bih[r1] + bhh[r1];
    const float bias2 = bih[r2] + bhh[r2];

    float wfcr[6];
    #pragma unroll
    for (int j = 0; j < 6; j++) wfcr[j] = Wfc[k*6 + j];
    const float bfcl  = bfc[k];
    const float woutl = (lane < 32) ? Wout[k] : 0.f;
    const float boutv = bout[0];

    float cgv[18], ssin[18];
    #pragma unroll
    for (int g = 0; g < 18; g++){
        int l = g / 6, q = g % 6;
        float a = 0.5f * qw[g];
        float cv = __cosf(a), sv = __sinf(a);
        cgv[g] = rfl(cv);
        unsigned sm = (unsigned)QM.S[l][q];
        ssin[g] = (__builtin_popcount(sm & lane) & 1) ? sv : -sv;
    }
    float wsgn[6];
    #pragma unroll
    for (int j = 0; j < 6; j++) wsgn[j] = (lane & (1u << j)) ? -1.f : 1.f;
    const bool qs[6] = { (lane & 32u) != 0, (lane & 16u) != 0, (lane & 8u) != 0,
                         (lane & 4u) != 0,  (lane & 2u) != 0,  (lane & 1u) != 0 };

    float h = 0.f, c = 0.f;
    const float* xbase = tS + (size_t)b * HC;

    float4 xf[8];
    #pragma unroll
    for (int j4 = 0; j4 < 8; j4++) xf[j4] = ((const float4*)xbase)[j4];

    #pragma clang loop unroll(disable)
    for (int s = 0; s < T_LEN; s++){
        float xt[32];
        #pragma unroll
        for (int j4 = 0; j4 < 8; j4++){
            xt[j4*4+0]=xf[j4].x; xt[j4*4+1]=xf[j4].y; xt[j4*4+2]=xf[j4].z; xt[j4*4+3]=xf[j4].w;
        }
        {
            int s2 = (s + 1 < T_LEN) ? s + 1 : s;
            const float4* np_ = (const float4*)(xbase + (size_t)s2*(B_SIZE*HC));
            #pragma unroll
            for (int j4 = 0; j4 < 8; j4++) xf[j4] = np_[j4];
        }

        float a1a = bias1, a1b = 0.f, a2a = bias2, a2b = 0.f;
        #pragma unroll
        for (int j = 0; j < 32; j += 2){
            a1a += xt[j]*wA[j];     a1b += xt[j+1]*wA[j+1];
            a2a += xt[j]*wB[j];     a2b += xt[j+1]*wB[j+1];
        }
        #pragma unroll
        for (int j = 0; j < 32; j += 2){
            float h0 = rdlane(h, j), h1 = rdlane(h, j+1);
            a1a += h0*uA[j];   a1b += h1*uA[j+1];
            a2a += h0*uB[j];   a2b += h1*uB[j+1];
        }
        float acc1 = a1a + a1b, acc2 = a2a + a2b;

        float sigA = fsigmoid(acc1);
        float argB = (lane < 32) ? acc2 : 0.5f*acc2;
        float tt   = ftanh(argB);
        float actB = (lane < 32) ? tt : (0.5f + 0.5f*tt);
        float fsig = xshuf<32>(sigA);
        float osig = xshuf<32>(actB);
        c = fsig*c + sigA*actB;
        float hn = osig * ftanh(c);

        hn = 3.99f * hn * (1.f - hn);
        float x0 = rdlane(hn, 0), y0 = rdlane(hn, 1);
        float xnv = 1.f - 1.4f*x0*x0 + y0;
        float ynv = 0.3f * x0;

        float ang[6];
        ang[0] = 0.5f*xnv; ang[1] = 0.5f*ynv;
        ang[2] = 0.5f*rdlane(hn, 2); ang[3] = 0.5f*rdlane(hn, 3);
        ang[4] = 0.5f*rdlane(hn, 4); ang[5] = 0.5f*rdlane(hn, 5);
        float ca[6], sa[6];
        #pragma unroll
        for (int j = 0; j < 6; j++){ ca[j] = __cosf(ang[j]); sa[j] = __sinf(ang[j]); }

        float fr[6], fi[6];
        #pragma unroll
        for (int i = 0; i < 6; i++){
            const int i1 = (i+1)%6, i2 = (i+2)%6;
            float cx=ca[i], sx=sa[i], cy=ca[i1], sy=sa[i1], cz=ca[i2], sz=sa[i2];
            float w0r = cy*cx, w0i = sy*sx;
            float w1r = sy*cx, w1i = -cy*sx;
            float q0r = cz*w0r + sz*w0i, q0i = cz*w0i - sz*w0r;
            float q1r = cz*w1r - sz*w1i, q1i = cz*w1i + sz*w1r;
            fr[i] = qs[i] ? q1r : q0r;
            fi[i] = qs[i] ? q1i : q0i;
        }
        float t01r = fr[0]*fr[1] - fi[0]*fi[1], t01i = fr[0]*fi[1] + fi[0]*fr[1];
        float t23r = fr[2]*fr[3] - fi[2]*fi[3], t23i = fr[2]*fi[3] + fi[2]*fr[3];
        float t45r = fr[4]*fr[5] - fi[4]*fi[5], t45i = fr[4]*fi[5] + fi[4]*fr[5];
        float t03r = t01r*t23r - t01i*t23i,     t03i = t01r*t23i + t01i*t23r;
        float ar   = t03r*t45r - t03i*t45i,     ai   = t03r*t45i + t03i*t45r;

        #define GATE(L,Q) { \
            constexpr int MM = QM.M[L][Q]; \
            float br = xshuf<MM>(ar), bi = xshuf<MM>(ai); \
            float cg = cgv[(L)*6+(Q)], ss = ssin[(L)*6+(Q)]; \
            ar = cg*ar + ss*br; ai = cg*ai + ss*bi; }
        GATE(0,0) GATE(0,1) GATE(0,2) GATE(0,3) GATE(0,4) GATE(0,5)
        GATE(1,0) GATE(1,1) GATE(1,2) GATE(1,3) GATE(1,4) GATE(1,5)
        GATE(2,0) GATE(2,1) GATE(2,2) GATE(2,3) GATE(2,4) GATE(2,5)
        #undef GATE

        float wp = ar*ar + ai*ai;
        wp = wsgn[0]*wp + xshuf< 1>(wp);
        wp = wsgn[1]*wp + xshuf< 2>(wp);
        wp = wsgn[2]*wp + xshuf< 4>(wp);
        wp = wsgn[3]*wp + xshuf< 8>(wp);
        wp = wsgn[4]*wp + xshuf<16>(wp);
        wp = wsgn[5]*wp + xshuf<32>(wp);
        float ev0 = rdlane(wp, QM.R[0]), ev1 = rdlane(wp, QM.R[1]);
        float ev2 = rdlane(wp, QM.R[2]), ev3 = rdlane(wp, QM.R[3]);
        float ev4 = rdlane(wp, QM.R[4]), ev5 = rdlane(wp, QM.R[5]);

        float upd = bfcl + (wfcr[0]*ev0 + wfcr[1]*ev1)
                         + (wfcr[2]*ev2 + wfcr[3]*ev3)
                         + (wfcr[4]*ev4 + wfcr[5]*ev5);

        float hsel = hn;
        hsel = (lane == 0u) ? xnv : hsel;
        hsel = (lane == 1u) ? ynv : hsel;
        h = hsel + upd;
    }

    float pv = (lane < 32) ? h*woutl : 0.f;
    #pragma unroll
    for (int off = 32; off; off >>= 1) pv += __shfl_xor(pv, off, 64);
    if (lane == 0) out[b] = fsigmoid(pv + boutv);
}

extern "C" void kernel_launch(void* const* d_in, const int* in_sizes, int n_in,
                              void* d_out, int out_size, void* d_ws, size_t ws_size,
                              hipStream_t stream)
{
    (void)in_sizes; (void)n_in; (void)out_size;
    const float* x    = (const float*)d_in[0];
    const float* w0   = (const float*)d_in[1];
    const float* b0   = (const float*)d_in[2];
    const float* w1   = (const float*)d_in[3];
    const float* b1   = (const float*)d_in[4];
    const float* w2   = (const float*)d_in[5];
    const float* b2   = (const float*)d_in[6];
    const float* Wih  = (const float*)d_in[7];
    const float* Whh  = (const float*)d_in[8];
    const float* bih  = (const float*)d_in[9];
    const float* bhh  = (const float*)d_in[10];
    const float* qw   = (const float*)d_in[11];
    const float* Wfc  = (const float*)d_in[12];
    const float* bfc  = (const float*)d_in[13];
    const float* Wout = (const float*)d_in[14];
    const float* bout = (const float*)d_in[15];
    float* out = (float*)d_out;

    const size_t tensorN = (size_t)B_SIZE*HC*T_LEN;        // 8M floats = 32 MB
    float* t0 = (float*)d_ws;                              // (B,32,T)
    float* G  = t0 + tensorN;                              // (T,B,128) = 134 MB
    const size_t need = (tensorN + (size_t)T_LEN*B_SIZE*128) * sizeof(float);

    conv0_kernel<<<2048, 256, 0, stream>>>(x, w0, b0, t0);
    if (ws_size >= need){
        conv12g_kernel<<<2048, 256, 0, stream>>>(t0, w1, b1, w2, b2, Wih, bih, bhh, G);
        scan_kernel<<<256, 256, 0, stream>>>(G, Whh, qw, Wfc, bfc, Wout, bout, out);
    } else {
        float* t1 = t0 + tensorN;
        float* tS = t0;
        convm_kernel<false><<<2048, 256, 0, stream>>>(t0, w1, b1, t1);
        convm_kernel<true ><<<2048, 256, 0, stream>>>(t1, w2, b2, tS);
        scan_legacy<<<256, 256, 0, stream>>>(tS, Wih, Whh, bih, bhh, qw, Wfc, bfc, Wout, bout, out);
    }
}

// Round 10
// 614.405 us; speedup vs baseline: 1.2168x; 1.0361x over previous
//
#include <hip/hip_runtime.h>

#define B_SIZE 1024
#define T_LEN  256
#define D_IN   64
#define HC     32

typedef int   v2i_t __attribute__((ext_vector_type(2)));
typedef float v2f   __attribute__((ext_vector_type(2)));

__device__ __forceinline__ float frcp(float x){ return __builtin_amdgcn_rcpf(x); }
__device__ __forceinline__ float rfl(float x){
    return __uint_as_float(__builtin_amdgcn_readfirstlane(__float_as_uint(x)));
}
__device__ __forceinline__ float rdlane(float x, int l){
    return __int_as_float(__builtin_amdgcn_readlane(__float_as_int(x), l));
}
__device__ __forceinline__ float ftanh(float x){
    return 1.f - 2.f*frcp(__expf(2.f*x) + 1.f);
}
__device__ __forceinline__ float fsigmoid(float x){
    return frcp(1.f + __expf(-x));
}

// cos/sin of (0.5*x): fold the half into the revolutions constant (1 mul + v_cos)
#define RKHALF 0.07957747154594767f
#if defined(__has_builtin)
#  if __has_builtin(__builtin_amdgcn_cosf) && __has_builtin(__builtin_amdgcn_sinf)
#    define HAVE_TRIGREV 1
#  endif
#endif
__device__ __forceinline__ float coshalf(float x){
#ifdef HAVE_TRIGREV
    return __builtin_amdgcn_cosf(x * RKHALF);
#else
    return __cosf(0.5f*x);
#endif
}
__device__ __forceinline__ float sinhalf(float x){
#ifdef HAVE_TRIGREV
    return __builtin_amdgcn_sinf(x * RKHALF);
#else
    return __sinf(0.5f*x);
#endif
}

template<int CTRL>
__device__ __forceinline__ int dppmov(int x){
    return __builtin_amdgcn_update_dpp(x, x, CTRL, 0xF, 0xF, false);
}

// xor within 16-lane rows, masks 1..15, pure DPP (1-2 ops)
template<int M>
__device__ __forceinline__ int dpp_xor(int x){
    static_assert(M >= 1 && M <= 15, "dpp_xor mask");
    constexpr int hi = M & 12;
    constexpr int q  = (hi == 4 || hi == 12) ? ((M & 3) ^ 3) : (M & 3);
    if constexpr (q == 1) x = dppmov<0xB1>(x);
    else if constexpr (q == 2) x = dppmov<0x4E>(x);
    else if constexpr (q == 3) x = dppmov<0x1B>(x);
    if constexpr (hi == 4)       x = dppmov<0x141>(x);   // ^7 -> with ^3 pre = ^4
    else if constexpr (hi == 8)  x = dppmov<0x128>(x);   // row_ror:8 = ^8
    else if constexpr (hi == 12) x = dppmov<0x140>(x);   // row_mirror = ^15
    return x;
}

#if defined(__has_builtin)
#  if __has_builtin(__builtin_amdgcn_permlane16_swap)
#    define HAVE_PL16 1
#  endif
#endif

// value of lane (lane ^ M) — fully VALU (R5/R6 HW-verified xor-trick for swaps)
template<int M>
__device__ __forceinline__ float xshuf(float xf){
    if constexpr (M == 0) return xf;
    int x = __float_as_int(xf);
    if constexpr (M & 15) x = dpp_xor<M & 15>(x);
    if constexpr (M & 16){
#ifdef HAVE_PL16
        v2i_t r = __builtin_amdgcn_permlane16_swap(x, x, false, false);
        x = r.x ^ r.y ^ x;
#else
        x = __builtin_amdgcn_ds_swizzle(x, (16 << 10) | 0x1F);
#endif
    }
    if constexpr (M & 32){
        v2i_t r = __builtin_amdgcn_permlane32_swap(x, x, false, false);
        x = r.x ^ r.y ^ x;
    }
    return __int_as_float(x);
}

// ---- compile-time GF(2) tracking of the CNOT-ring basis relabeling (R3-verified) ----
struct QMasks { int M[3][6]; int S[3][6]; int R[6]; };
constexpr QMasks qmasks(){
    QMasks qm{};
    unsigned m[6], n[6];
    for (int i = 0; i < 6; i++){ m[i] = 1u << i; n[i] = 1u << i; }
    for (int l = 0; l < 3; l++){
        for (int q = 0; q < 6; q++){
            unsigned u = m[q], r = 0;
            for (int i = 0; i < 6; i++) if ((u >> i) & 1u) r |= (32u >> i);
            qm.S[l][q] = (int)r;
            unsigned u2 = 0;
            for (int i = 0; i < 6; i++) u2 |= ((n[i] >> q) & 1u) << i;
            unsigned r2 = 0;
            for (int i = 0; i < 6; i++) if ((u2 >> i) & 1u) r2 |= (32u >> i);
            qm.M[l][q] = (int)r2;
        }
        for (int q = 0; q < 6; q++) m[(q + 1) % 6] ^= m[q];
        n[0] ^= n[5];
        for (int q = 4; q >= 0; q--) n[q + 1] ^= n[q];
    }
    for (int i = 0; i < 6; i++){
        unsigned u = m[i], r = 0;
        for (int j = 0; j < 6; j++) if ((u >> j) & 1u) r |= (32u >> j);
        qm.R[i] = (int)r;
    }
    return qm;
}
constexpr QMasks QM = qmasks();

// -------- conv0: x (B,T,64) -> t0 (B,32,T); split-d staging for 3 blocks/CU --------
__global__ __launch_bounds__(256) void conv0_kernel(const float* __restrict__ x,
    const float* __restrict__ w0, const float* __restrict__ b0, float* __restrict__ out)
{
    __shared__ float xs[130*33];                 // half-d tile (d 0..31 or 32..63)
    __shared__ __align__(16) float wl[192*36];   // [r=d*3+k][c]
    const int tid = threadIdx.x;
    const int b  = blockIdx.x >> 1;
    const int s0 = (blockIdx.x & 1) * 128;

    for (int idx = tid; idx < 192*32; idx += 256){
        int c = idx / 192, r = idx - c*192;
        wl[r*36 + c] = w0[idx];
    }

    const int c0 = (tid & 7) * 4;
    const int sl = (tid >> 3) * 4;
    float acc[4][4];
    #pragma unroll
    for (int ci = 0; ci < 4; ci++){
        float bb = b0[c0+ci];
        #pragma unroll
        for (int m = 0; m < 4; m++) acc[ci][m] = bb;
    }

    for (int half = 0; half < 2; half++){
        __syncthreads();    // 1st: wl staged; 2nd: previous half's xs reads done
        for (int idx = tid; idx < 130*32; idx += 256){
            int r = idx >> 5, d = idx & 31;
            int s = s0 - 1 + r;
            float v = 0.f;
            if (s >= 0 && s < T_LEN) v = x[(size_t)b*(T_LEN*D_IN) + (size_t)s*D_IN + half*32 + d];
            xs[r*33 + d] = v;
        }
        __syncthreads();
        for (int d = 0; d < 32; d++){
            float xv[6];
            #pragma unroll
            for (int o = 0; o < 6; o++) xv[o] = xs[(sl+o)*33 + d];
            const int dd = half*32 + d;
            #pragma unroll
            for (int kk = 0; kk < 3; kk++){
                const float4 wv = *(const float4*)&wl[(dd*3+kk)*36 + c0];
                float w4[4] = {wv.x, wv.y, wv.z, wv.w};
                #pragma unroll
                for (int ci = 0; ci < 4; ci++)
                    #pragma unroll
                    for (int m = 0; m < 4; m++)
                        acc[ci][m] += xv[m+kk]*w4[ci];
            }
        }
    }
    #pragma unroll
    for (int ci = 0; ci < 4; ci++){
        float4 v;
        v.x = fmaxf(acc[ci][0], 0.f); v.y = fmaxf(acc[ci][1], 0.f);
        v.z = fmaxf(acc[ci][2], 0.f); v.w = fmaxf(acc[ci][3], 0.f);
        *(float4*)&out[(size_t)b*(HC*T_LEN) + (size_t)(c0+ci)*T_LEN + (s0+sl)] = v;
    }
}

// ----- fused conv1 + conv2 + gates: t0 (B,32,T) -> G[(s*B+b)*128+r], all in-LDS -----
// R10: phase-3 reads ONE b32 per lane (distributed channels) + v_readlane
// broadcasts instead of 8 broadcast b128 per s — converts DS-bound to VALU-bound.
// Accumulation order identical to R9 -> bit-identical G.
__global__ __launch_bounds__(256) void conv12g_kernel(const float* __restrict__ t0g,
    const float* __restrict__ w1, const float* __restrict__ b1,
    const float* __restrict__ w2, const float* __restrict__ b2,
    const float* __restrict__ Wih, const float* __restrict__ bih,
    const float* __restrict__ bhh, float* __restrict__ G)
{
    __shared__ __align__(16) float smem[4608 + 3456 + 4290];  // 49.4 KB
    float* t0t = smem;                 // [132][33]  (4356 used of 4608)
    float* t2t = smem;                 // [128][36]  overlays t0t region (4608)
    float* wlr = smem + 4608;          // [96][36]   w1 then w2
    float* t1t = smem + 4608 + 3456;   // [130][33]
    const int tid = threadIdx.x;
    const int b  = blockIdx.x >> 1;
    const int s0 = (blockIdx.x & 1) * 128;

    // ---- stage t0 tile (rows s0-2 .. s0+129) + w1 ----
    for (int idx = tid; idx < 132*32; idx += 256){
        int ci = idx / 132, r = idx - ci*132;
        int s = s0 - 2 + r;
        float v = 0.f;
        if (s >= 0 && s < T_LEN) v = t0g[(size_t)b*(HC*T_LEN) + (size_t)ci*T_LEN + s];
        t0t[r*33 + ci] = v;
    }
    for (int idx = tid; idx < 96*32; idx += 256){
        int c = idx / 96, r = idx - c*96;
        wlr[r*36 + c] = w1[idx];
    }
    __syncthreads();

    // ---- phase 1: conv1, 130 output rows; groups 30,31 take 5 rows each ----
    const int c0 = (tid & 7) * 4;
    const int g  = tid >> 3;
    const int base1 = (g < 30) ? 4*g : (120 + 5*(g - 30));
    const int nr1   = (g < 30) ? 4 : 5;
    {
        float acc[4][5];
        #pragma unroll
        for (int ci = 0; ci < 4; ci++){
            float bb = b1[c0+ci];
            #pragma unroll
            for (int m = 0; m < 5; m++) acc[ci][m] = bb;
        }
        for (int ci2 = 0; ci2 < 32; ci2++){
            float xv[7];
            #pragma unroll
            for (int o = 0; o < 7; o++) xv[o] = t0t[(base1+o)*33 + ci2];
            #pragma unroll
            for (int kk = 0; kk < 3; kk++){
                const float4 wv = *(const float4*)&wlr[(ci2*3+kk)*36 + c0];
                float w4[4] = {wv.x, wv.y, wv.z, wv.w};
                #pragma unroll
                for (int ci = 0; ci < 4; ci++)
                    #pragma unroll
                    for (int m = 0; m < 5; m++)
                        acc[ci][m] += xv[m+kk]*w4[ci];
            }
        }
        // write t1t; rows at absolute s outside [0,T) are conv2 padding -> 0
        #pragma unroll
        for (int m = 0; m < 5; m++){
            if (m < nr1){
                const int rt = base1 + m;
                const int s_act = s0 - 1 + rt;
                const bool inb = (s_act >= 0) && (s_act < T_LEN);
                #pragma unroll
                for (int ci = 0; ci < 4; ci++)
                    t1t[rt*33 + c0 + ci] = inb ? fmaxf(acc[ci][m], 0.f) : 0.f;
            }
        }
    }
    __syncthreads();   // conv1 reads of t0t/wlr done; t1t written

    // ---- stage w2 (overwrites w1 region) ----
    for (int idx = tid; idx < 96*32; idx += 256){
        int c = idx / 96, r = idx - c*96;
        wlr[r*36 + c] = w2[idx];
    }
    __syncthreads();

    // ---- phase 2: conv2, 128 output rows into t2t (overlays t0t) ----
    const int base2 = 4*g;
    {
        float acc[4][4];
        #pragma unroll
        for (int ci = 0; ci < 4; ci++){
            float bb = b2[c0+ci];
            #pragma unroll
            for (int m = 0; m < 4; m++) acc[ci][m] = bb;
        }
        for (int ci2 = 0; ci2 < 32; ci2++){
            float xv[6];
            #pragma unroll
            for (int o = 0; o < 6; o++) xv[o] = t1t[(base2+o)*33 + ci2];
            #pragma unroll
            for (int kk = 0; kk < 3; kk++){
                const float4 wv = *(const float4*)&wlr[(ci2*3+kk)*36 + c0];
                float w4[4] = {wv.x, wv.y, wv.z, wv.w};
                #pragma unroll
                for (int ci = 0; ci < 4; ci++)
                    #pragma unroll
                    for (int m = 0; m < 4; m++)
                        acc[ci][m] += xv[m+kk]*w4[ci];
            }
        }
        __syncthreads();   // t0t region reads fully done before overlay write
        #pragma unroll
        for (int m = 0; m < 4; m++){
            float4 v;
            v.x = fmaxf(acc[0][m], 0.f); v.y = fmaxf(acc[1][m], 0.f);
            v.z = fmaxf(acc[2][m], 0.f); v.w = fmaxf(acc[3][m], 0.f);
            *(float4*)&t2t[(base2+m)*36 + c0] = v;
        }
    }
    __syncthreads();

    // ---- phase 3: gates GEMM, lane r handles gate rows r and r+64 ----
    // Packed {rowA,rowB} weights; x via 1 distributed b32 + readlane broadcasts.
    const int r = tid & 63;
    const int wvv = tid >> 6;
    v2f uP[32];
    #pragma unroll
    for (int j4 = 0; j4 < 8; j4++){
        float4 a = ((const float4*)Wih)[r*8 + j4];
        float4 e = ((const float4*)Wih)[(r+64)*8 + j4];
        uP[j4*4+0] = v2f{a.x, e.x}; uP[j4*4+1] = v2f{a.y, e.y};
        uP[j4*4+2] = v2f{a.z, e.z}; uP[j4*4+3] = v2f{a.w, e.w};
    }
    const float brA = bih[r]    + bhh[r];
    const float brB = bih[r+64] + bhh[r+64];

    for (int ss = wvv; ss < 128; ss += 4){
        const float xval = t2t[ss*36 + (tid & 31)];   // distributed, conflict-free
        v2f A0 = v2f{brA, brB}, A1 = v2f{0.f,0.f}, A2 = v2f{0.f,0.f}, A3 = v2f{0.f,0.f};
        #pragma unroll
        for (int j4 = 0; j4 < 8; j4++){
            float x0 = rdlane(xval, j4*4+0), x1 = rdlane(xval, j4*4+1);
            float x2 = rdlane(xval, j4*4+2), x3 = rdlane(xval, j4*4+3);
            A0 += x0*uP[j4*4+0]; A1 += x1*uP[j4*4+1];
            A2 += x2*uP[j4*4+2]; A3 += x3*uP[j4*4+3];
        }
        const size_t gi = ((size_t)(s0+ss)*B_SIZE + b)*128 + r;
        G[gi]      = (A0.x+A1.x)+(A2.x+A3.x);
        G[gi + 64] = (A0.y+A1.y)+(A2.y+A3.y);
    }
}

// ------------- mid conv (fallback only): (B,32,T) -> (B,32,T) or (T,B,32) -------------
template<bool TOUT>
__global__ __launch_bounds__(256) void convm_kernel(const float* __restrict__ in,
    const float* __restrict__ w, const float* __restrict__ bias, float* __restrict__ out)
{
    __shared__ __align__(16) float xs[130*33];
    __shared__ __align__(16) float wl[96*36];
    const int tid = threadIdx.x;
    const int b  = blockIdx.x >> 1;
    const int s0 = (blockIdx.x & 1) * 128;

    for (int idx = tid; idx < 32*130; idx += 256){
        int ci = idx / 130; int r = idx - ci*130;
        int s = s0 - 1 + r;
        float v = 0.f;
        if (s >= 0 && s < T_LEN) v = in[(size_t)b*(HC*T_LEN) + (size_t)ci*T_LEN + s];
        xs[r*33 + ci] = v;
    }
    for (int idx = tid; idx < 96*32; idx += 256){
        int c = idx / 96, r = idx - c*96;
        wl[r*36 + c] = w[idx];
    }
    __syncthreads();

    const int c0 = (tid & 7) * 4;
    const int sl = (tid >> 3) * 4;
    float acc[4][4];
    #pragma unroll
    for (int ci = 0; ci < 4; ci++){
        float bb = bias[c0+ci];
        #pragma unroll
        for (int m = 0; m < 4; m++) acc[ci][m] = bb;
    }
    for (int ci2 = 0; ci2 < 32; ci2++){
        float xv[6];
        #pragma unroll
        for (int o = 0; o < 6; o++) xv[o] = xs[(sl+o)*33 + ci2];
        #pragma unroll
        for (int kk = 0; kk < 3; kk++){
            const float4 wv = *(const float4*)&wl[(ci2*3+kk)*36 + c0];
            float w4[4] = {wv.x, wv.y, wv.z, wv.w};
            #pragma unroll
            for (int ci = 0; ci < 4; ci++)
                #pragma unroll
                for (int m = 0; m < 4; m++)
                    acc[ci][m] += xv[m+kk]*w4[ci];
        }
    }
    if (!TOUT){
        #pragma unroll
        for (int ci = 0; ci < 4; ci++){
            float4 v;
            v.x = fmaxf(acc[ci][0], 0.f); v.y = fmaxf(acc[ci][1], 0.f);
            v.z = fmaxf(acc[ci][2], 0.f); v.w = fmaxf(acc[ci][3], 0.f);
            *(float4*)&out[(size_t)b*(HC*T_LEN) + (size_t)(c0+ci)*T_LEN + (s0+sl)] = v;
        }
    } else {
        #pragma unroll
        for (int m = 0; m < 4; m++){
            int s = s0 + sl + m;
            float4 v;
            v.x = fmaxf(acc[0][m], 0.f); v.y = fmaxf(acc[1][m], 0.f);
            v.z = fmaxf(acc[2][m], 0.f); v.w = fmaxf(acc[3][m], 0.f);
            *(float4*)&out[(size_t)s*(B_SIZE*HC) + (size_t)b*HC + c0] = v;
        }
    }
}

// ------------- scan v4: G-fed, DS-free loop; R10 instruction diet -------------
__global__ __launch_bounds__(256, 1) void scan_kernel(
    const float* __restrict__ G,   const float* __restrict__ Whh,
    const float* __restrict__ qw,  const float* __restrict__ Wfc,
    const float* __restrict__ bfc, const float* __restrict__ Wout,
    const float* __restrict__ bout, float* __restrict__ out)
{
    const unsigned lane = threadIdx.x & 63u;
    const int wv   = threadIdx.x >> 6;
    const int b    = __builtin_amdgcn_readfirstlane(blockIdx.x * 4 + wv);
    const int r1 = lane, r2 = lane + 64;       // gate rows: [i f | g o]
    const int k  = lane & 31;

    v2f uAB[32];
    #pragma unroll
    for (int j4 = 0; j4 < 8; j4++){
        float4 d_ = ((const float4*)Whh)[r1*8 + j4];
        float4 e  = ((const float4*)Whh)[r2*8 + j4];
        uAB[j4*4+0] = v2f{d_.x, e.x}; uAB[j4*4+1] = v2f{d_.y, e.y};
        uAB[j4*4+2] = v2f{d_.z, e.z}; uAB[j4*4+3] = v2f{d_.w, e.w};
    }

    float wfcr[6];
    #pragma unroll
    for (int j = 0; j < 6; j++) wfcr[j] = Wfc[k*6 + j];
    const float bfcl  = bfc[k];
    const float woutl = (lane < 32) ? Wout[k] : 0.f;
    const float boutv = bout[0];

    float cgv[18], ssin[18];
    #pragma unroll
    for (int g = 0; g < 18; g++){
        int l = g / 6, q = g % 6;
        float a = 0.5f * qw[g];
        float cv = __cosf(a), sv = __sinf(a);
        cgv[g] = rfl(cv);
        unsigned sm = (unsigned)QM.S[l][q];
        ssin[g] = (__builtin_popcount(sm & lane) & 1) ? sv : -sv;
    }
    float wsgn[6];
    #pragma unroll
    for (int j = 0; j < 6; j++) wsgn[j] = (lane & (1u << j)) ? -1.f : 1.f;
    const bool qs[6] = { (lane & 32u) != 0, (lane & 16u) != 0, (lane & 8u) != 0,
                         (lane & 4u) != 0,  (lane & 2u) != 0,  (lane & 1u) != 0 };
    float sgnq[6];
    #pragma unroll
    for (int j = 0; j < 6; j++) sgnq[j] = qs[j] ? -1.f : 1.f;

    float h = 0.f, c = 0.f;
    const float* gbase = G + (size_t)b*128;
    float g1 = gbase[r1], g2 = gbase[r2];

    #pragma clang loop unroll(disable)
    for (int s = 0; s < T_LEN; s++){
        const float cg1 = g1, cg2 = g2;
        {
            int s2 = (s + 1 < T_LEN) ? s + 1 : s;
            const float* gn = gbase + (size_t)s2*(B_SIZE*128);
            g1 = gn[r1]; g2 = gn[r2];
        }

        v2f a0 = v2f{cg1, cg2}, a1 = v2f{0.f,0.f}, a2 = v2f{0.f,0.f}, a3 = v2f{0.f,0.f};
        #pragma unroll
        for (int j = 0; j < 32; j += 4){
            float h0 = rdlane(h, j),   h1 = rdlane(h, j+1);
            float h2 = rdlane(h, j+2), h3 = rdlane(h, j+3);
            a0 += h0*uAB[j]; a1 += h1*uAB[j+1]; a2 += h2*uAB[j+2]; a3 += h3*uAB[j+3];
        }
        v2f accv = (a0+a1)+(a2+a3);
        float acc1 = accv.x, acc2 = accv.y;

        float sigA = fsigmoid(acc1);
        float argB = (lane < 32) ? acc2 : 0.5f*acc2;
        float tt   = ftanh(argB);
        float actB = (lane < 32) ? tt : (0.5f + 0.5f*tt);
        float fsig = xshuf<32>(sigA);
        float osig = xshuf<32>(actB);
        c = fsig*c + sigA*actB;
        float hn = osig * ftanh(c);

        hn = 3.99f * hn * (1.f - hn);
        float x0 = rdlane(hn, 0), y0 = rdlane(hn, 1);
        float xnv = 1.f - 1.4f*x0*x0 + y0;
        float ynv = 0.3f * x0;

        // ---- product-state init: half-angle trig folded; 2-select qubit form ----
        float hv[6];
        hv[0] = xnv; hv[1] = ynv;
        hv[2] = rdlane(hn, 2); hv[3] = rdlane(hn, 3);
        hv[4] = rdlane(hn, 4); hv[5] = rdlane(hn, 5);
        float ca[6], sa[6];
        #pragma unroll
        for (int j = 0; j < 6; j++){ ca[j] = coshalf(hv[j]); sa[j] = sinhalf(hv[j]); }

        float fr[6], fi[6];
        #pragma unroll
        for (int i = 0; i < 6; i++){
            const int i1 = (i+1)%6, i2 = (i+2)%6;
            float cx=ca[i], sx=sa[i], cy=ca[i1], sy=sa[i1], cz=ca[i2], sz=sa[i2];
            // qb=0: w_r=cy*cx, w_i=sy*sx, f = (cz - i sz)(w_r + i w_i)
            // qb=1: w_r=sy*cx, w_i=-cy*sx, f = (cz + i sz)(w_r + i w_i)
            float cyp = qs[i] ? sy : cy;
            float syp = qs[i] ? -cy : sy;
            float szs = sz * sgnq[i];          // +sz (qb=0) / -sz (qb=1)
            float w_r = cyp*cx, w_i = syp*sx;
            fr[i] = cz*w_r + szs*w_i;
            fi[i] = cz*w_i - szs*w_r;
        }
        v2f t01 = v2f{fr[0]*fr[1] - fi[0]*fi[1], fr[0]*fi[1] + fi[0]*fr[1]};
        v2f t23 = v2f{fr[2]*fr[3] - fi[2]*fi[3], fr[2]*fi[3] + fi[2]*fr[3]};
        v2f t45 = v2f{fr[4]*fr[5] - fi[4]*fi[5], fr[4]*fi[5] + fi[4]*fr[5]};
        v2f t03 = v2f{t01.x*t23.x - t01.y*t23.y, t01.x*t23.y + t01.y*t23.x};
        v2f av  = v2f{t03.x*t45.x - t03.y*t45.y, t03.x*t45.y + t03.y*t45.x};

        #define GATE(L,Q) { \
            constexpr int MM = QM.M[L][Q]; \
            v2f bv; bv.x = xshuf<MM>(av.x); bv.y = xshuf<MM>(av.y); \
            av = cgv[(L)*6+(Q)]*av + ssin[(L)*6+(Q)]*bv; }
        GATE(0,0) GATE(0,1) GATE(0,2) GATE(0,3) GATE(0,4) GATE(0,5)
        GATE(1,0) GATE(1,1) GATE(1,2) GATE(1,3) GATE(1,4) GATE(1,5)
        GATE(2,0) GATE(2,1) GATE(2,2) GATE(2,3) GATE(2,4) GATE(2,5)
        #undef GATE

        float wp = av.x*av.x + av.y*av.y;
        wp = wsgn[0]*wp + xshuf< 1>(wp);
        wp = wsgn[1]*wp + xshuf< 2>(wp);
        wp = wsgn[2]*wp + xshuf< 4>(wp);
        wp = wsgn[3]*wp + xshuf< 8>(wp);
        wp = wsgn[4]*wp + xshuf<16>(wp);
        wp = wsgn[5]*wp + xshuf<32>(wp);
        float ev0 = rdlane(wp, QM.R[0]), ev1 = rdlane(wp, QM.R[1]);
        float ev2 = rdlane(wp, QM.R[2]), ev3 = rdlane(wp, QM.R[3]);
        float ev4 = rdlane(wp, QM.R[4]), ev5 = rdlane(wp, QM.R[5]);

        float upd = bfcl + (wfcr[0]*ev0 + wfcr[1]*ev1)
                         + (wfcr[2]*ev2 + wfcr[3]*ev3)
                         + (wfcr[4]*ev4 + wfcr[5]*ev5);

        float hsel = hn;
        hsel = (lane == 0u) ? xnv : hsel;
        hsel = (lane == 1u) ? ynv : hsel;
        h = hsel + upd;
    }

    float pv = (lane < 32) ? h*woutl : 0.f;
    #pragma unroll
    for (int off = 32; off; off >>= 1) pv += __shfl_xor(pv, off, 64);
    if (lane == 0) out[b] = fsigmoid(pv + boutv);
}

// ---------------- legacy scan (R5-proven) — fallback if ws too small ----------------
__global__ __launch_bounds__(256, 1) void scan_legacy(
    const float* __restrict__ tS,
    const float* __restrict__ Wih, const float* __restrict__ Whh,
    const float* __restrict__ bih, const float* __restrict__ bhh,
    const float* __restrict__ qw,  const float* __restrict__ Wfc,
    const float* __restrict__ bfc, const float* __restrict__ Wout,
    const float* __restrict__ bout, float* __restrict__ out)
{
    const unsigned lane = threadIdx.x & 63u;
    const int wv   = threadIdx.x >> 6;
    const int b    = __builtin_amdgcn_readfirstlane(blockIdx.x * 4 + wv);
    const int r1 = lane, r2 = lane + 64;
    const int k  = lane & 31;

    float wA[32], wB[32], uA[32], uB[32];
    #pragma unroll
    for (int j4 = 0; j4 < 8; j4++){
        float4 a  = ((const float4*)Wih)[r1*8 + j4];
        float4 c_ = ((const float4*)Wih)[r2*8 + j4];
        float4 d_ = ((const float4*)Whh)[r1*8 + j4];
        float4 e  = ((const float4*)Whh)[r2*8 + j4];
        wA[j4*4+0]=a.x;  wA[j4*4+1]=a.y;  wA[j4*4+2]=a.z;  wA[j4*4+3]=a.w;
        wB[j4*4+0]=c_.x; wB[j4*4+1]=c_.y; wB[j4*4+2]=c_.z; wB[j4*4+3]=c_.w;
        uA[j4*4+0]=d_.x; uA[j4*4+1]=d_.y; uA[j4*4+2]=d_.z; uA[j4*4+3]=d_.w;
        uB[j4*4+0]=e.x;  uB[j4*4+1]=e.y;  uB[j4*4+2]=e.z;  uB[j4*4+3]=e.w;
    }
    const float bias1 = bih[r1] + bhh[r1];
    const float bias2 = bih[r2] + bhh[r2];

    float wfcr[6];
    #pragma unroll
    for (int j = 0; j < 6; j++) wfcr[j] = Wfc[k*6 + j];
    const float bfcl  = bfc[k];
    const float woutl = (lane < 32) ? Wout[k] : 0.f;
    const float boutv = bout[0];

    float cgv[18], ssin[18];
    #pragma unroll
    for (int g = 0; g < 18; g++){
        int l = g / 6, q = g % 6;
        float a = 0.5f * qw[g];
        float cv = __cosf(a), sv = __sinf(a);
        cgv[g] = rfl(cv);
        unsigned sm = (unsigned)QM.S[l][q];
        ssin[g] = (__builtin_popcount(sm & lane) & 1) ? sv : -sv;
    }
    float wsgn[6];
    #pragma unroll
    for (int j = 0; j < 6; j++) wsgn[j] = (lane & (1u << j)) ? -1.f : 1.f;
    const bool qs[6] = { (lane & 32u) != 0, (lane & 16u) != 0, (lane & 8u) != 0,
                         (lane & 4u) != 0,  (lane & 2u) != 0,  (lane & 1u) != 0 };

    float h = 0.f, c = 0.f;
    const float* xbase = tS + (size_t)b * HC;

    float4 xf[8];
    #pragma unroll
    for (int j4 = 0; j4 < 8; j4++) xf[j4] = ((const float4*)xbase)[j4];

    #pragma clang loop unroll(disable)
    for (int s = 0; s < T_LEN; s++){
        float xt[32];
        #pragma unroll
        for (int j4 = 0; j4 < 8; j4++){
            xt[j4*4+0]=xf[j4].x; xt[j4*4+1]=xf[j4].y; xt[j4*4+2]=xf[j4].z; xt[j4*4+3]=xf[j4].w;
        }
        {
            int s2 = (s + 1 < T_LEN) ? s + 1 : s;
            const float4* np_ = (const float4*)(xbase + (size_t)s2*(B_SIZE*HC));
            #pragma unroll
            for (int j4 = 0; j4 < 8; j4++) xf[j4] = np_[j4];
        }

        float a1a = bias1, a1b = 0.f, a2a = bias2, a2b = 0.f;
        #pragma unroll
        for (int j = 0; j < 32; j += 2){
            a1a += xt[j]*wA[j];     a1b += xt[j+1]*wA[j+1];
            a2a += xt[j]*wB[j];     a2b += xt[j+1]*wB[j+1];
        }
        #pragma unroll
        for (int j = 0; j < 32; j += 2){
            float h0 = rdlane(h, j), h1 = rdlane(h, j+1);
            a1a += h0*uA[j];   a1b += h1*uA[j+1];
            a2a += h0*uB[j];   a2b += h1*uB[j+1];
        }
        float acc1 = a1a + a1b, acc2 = a2a + a2b;

        float sigA = fsigmoid(acc1);
        float argB = (lane < 32) ? acc2 : 0.5f*acc2;
        float tt   = ftanh(argB);
        float actB = (lane < 32) ? tt : (0.5f + 0.5f*tt);
        float fsig = xshuf<32>(sigA);
        float osig = xshuf<32>(actB);
        c = fsig*c + sigA*actB;
        float hn = osig * ftanh(c);

        hn = 3.99f * hn * (1.f - hn);
        float x0 = rdlane(hn, 0), y0 = rdlane(hn, 1);
        float xnv = 1.f - 1.4f*x0*x0 + y0;
        float ynv = 0.3f * x0;

        float ang[6];
        ang[0] = 0.5f*xnv; ang[1] = 0.5f*ynv;
        ang[2] = 0.5f*rdlane(hn, 2); ang[3] = 0.5f*rdlane(hn, 3);
        ang[4] = 0.5f*rdlane(hn, 4); ang[5] = 0.5f*rdlane(hn, 5);
        float ca[6], sa[6];
        #pragma unroll
        for (int j = 0; j < 6; j++){ ca[j] = __cosf(ang[j]); sa[j] = __sinf(ang[j]); }

        float fr[6], fi[6];
        #pragma unroll
        for (int i = 0; i < 6; i++){
            const int i1 = (i+1)%6, i2 = (i+2)%6;
            float cx=ca[i], sx=sa[i], cy=ca[i1], sy=sa[i1], cz=ca[i2], sz=sa[i2];
            float w0r = cy*cx, w0i = sy*sx;
            float w1r = sy*cx, w1i = -cy*sx;
            float q0r = cz*w0r + sz*w0i, q0i = cz*w0i - sz*w0r;
            float q1r = cz*w1r - sz*w1i, q1i = cz*w1i + sz*w1r;
            fr[i] = qs[i] ? q1r : q0r;
            fi[i] = qs[i] ? q1i : q0i;
        }
        float t01r = fr[0]*fr[1] - fi[0]*fi[1], t01i = fr[0]*fi[1] + fi[0]*fr[1];
        float t23r = fr[2]*fr[3] - fi[2]*fi[3], t23i = fr[2]*fi[3] + fi[2]*fr[3];
        float t45r = fr[4]*fr[5] - fi[4]*fi[5], t45i = fr[4]*fi[5] + fi[4]*fr[5];
        float t03r = t01r*t23r - t01i*t23i,     t03i = t01r*t23i + t01i*t23r;
        float ar   = t03r*t45r - t03i*t45i,     ai   = t03r*t45i + t03i*t45r;

        #define GATE(L,Q) { \
            constexpr int MM = QM.M[L][Q]; \
            float br = xshuf<MM>(ar), bi = xshuf<MM>(ai); \
            float cg = cgv[(L)*6+(Q)], ss = ssin[(L)*6+(Q)]; \
            ar = cg*ar + ss*br; ai = cg*ai + ss*bi; }
        GATE(0,0) GATE(0,1) GATE(0,2) GATE(0,3) GATE(0,4) GATE(0,5)
        GATE(1,0) GATE(1,1) GATE(1,2) GATE(1,3) GATE(1,4) GATE(1,5)
        GATE(2,0) GATE(2,1) GATE(2,2) GATE(2,3) GATE(2,4) GATE(2,5)
        #undef GATE

        float wp = ar*ar + ai*ai;
        wp = wsgn[0]*wp + xshuf< 1>(wp);
        wp = wsgn[1]*wp + xshuf< 2>(wp);
        wp = wsgn[2]*wp + xshuf< 4>(wp);
        wp = wsgn[3]*wp + xshuf< 8>(wp);
        wp = wsgn[4]*wp + xshuf<16>(wp);
        wp = wsgn[5]*wp + xshuf<32>(wp);
        float ev0 = rdlane(wp, QM.R[0]), ev1 = rdlane(wp, QM.R[1]);
        float ev2 = rdlane(wp, QM.R[2]), ev3 = rdlane(wp, QM.R[3]);
        float ev4 = rdlane(wp, QM.R[4]), ev5 = rdlane(wp, QM.R[5]);

        float upd = bfcl + (wfcr[0]*ev0 + wfcr[1]*ev1)
                         + (wfcr[2]*ev2 + wfcr[3]*ev3)
                         + (wfcr[4]*ev4 + wfcr[5]*ev5);

        float hsel = hn;
        hsel = (lane == 0u) ? xnv : hsel;
        hsel = (lane == 1u) ? ynv : hsel;
        h = hsel + upd;
    }

    float pv = (lane < 32) ? h*woutl : 0.f;
    #pragma unroll
    for (int off = 32; off; off >>= 1) pv += __shfl_xor(pv, off, 64);
    if (lane == 0) out[b] = fsigmoid(pv + boutv);
}

extern "C" void kernel_launch(void* const* d_in, const int* in_sizes, int n_in,
                              void* d_out, int out_size, void* d_ws, size_t ws_size,
                              hipStream_t stream)
{
    (void)in_sizes; (void)n_in; (void)out_size;
    const float* x    = (const float*)d_in[0];
    const float* w0   = (const float*)d_in[1];
    const float* b0   = (const float*)d_in[2];
    const float* w1   = (const float*)d_in[3];
    const float* b1   = (const float*)d_in[4];
    const float* w2   = (const float*)d_in[5];
    const float* b2   = (const float*)d_in[6];
    const float* Wih  = (const float*)d_in[7];
    const float* Whh  = (const float*)d_in[8];
    const float* bih  = (const float*)d_in[9];
    const float* bhh  = (const float*)d_in[10];
    const float* qw   = (const float*)d_in[11];
    const float* Wfc  = (const float*)d_in[12];
    const float* bfc  = (const float*)d_in[13];
    const float* Wout = (const float*)d_in[14];
    const float* bout = (const float*)d_in[15];
    float* out = (float*)d_out;

    const size_t tensorN = (size_t)B_SIZE*HC*T_LEN;        // 8M floats = 32 MB
    float* t0 = (float*)d_ws;                              // (B,32,T)
    float* G  = t0 + tensorN;                              // (T,B,128) = 134 MB
    const size_t need = (tensorN + (size_t)T_LEN*B_SIZE*128) * sizeof(float);

    conv0_kernel<<<2048, 256, 0, stream>>>(x, w0, b0, t0);
    if (ws_size >= need){
        conv12g_kernel<<<2048, 256, 0, stream>>>(t0, w1, b1, w2, b2, Wih, bih, bhh, G);
        scan_kernel<<<256, 256, 0, stream>>>(G, Whh, qw, Wfc, bfc, Wout, bout, out);
    } else {
        float* t1 = t0 + tensorN;
        float* tS = t0;
        convm_kernel<false><<<2048, 256, 0, stream>>>(t0, w1, b1, t1);
        convm_kernel<true ><<<2048, 256, 0, stream>>>(t1, w2, b2, tS);
        scan_legacy<<<256, 256, 0, stream>>>(tS, Wih, Whh, bih, bhh, qw, Wfc, bfc, Wout, bout, out);
    }
}